// Round 14
// baseline (299.892 us; speedup 1.0000x reference)
//
#include <hip/hip_runtime.h>
#include <stdint.h>

#define DEV __device__ __forceinline__

typedef __attribute__((ext_vector_type(8))) short short8;
typedef __attribute__((ext_vector_type(8))) unsigned short ushort8;
typedef __attribute__((ext_vector_type(4))) float f32x4;
typedef __attribute__((ext_vector_type(16))) float f32x16;
typedef __attribute__((ext_vector_type(2))) unsigned int uint2v;

DEV unsigned short f2bf(float f) {
  union { float f; uint32_t u; } v; v.f = f;
  uint32_t u = v.u;
  u += 0x7FFFu + ((u >> 16) & 1);  // RNE
  return (unsigned short)(u >> 16);
}
DEV float bf2f(unsigned short s) {
  union { uint32_t u; float f; } v; v.u = ((uint32_t)s) << 16;
  return v.f;
}
DEV float exp2_fast(float x) {
  float r; asm("v_exp_f32 %0, %1" : "=v"(r) : "v"(x)); return r;
}
DEV uint32_t cvt_pk_bf16(float lo, float hi) {
  uint32_t r; asm("v_cvt_pk_bf16_f32 %0, %1, %2" : "=v"(r) : "v"(lo), "v"(hi)); return r;
}

DEV void async_ld16(void* lds, const void* g) {
  __builtin_amdgcn_global_load_lds(
      (const __attribute__((address_space(1))) unsigned int*)g,
      (__attribute__((address_space(3))) unsigned int*)lds, 16, 0, 0);
}

// ---------------- cast fp32 -> bf16 (vectorized) ----------------
__global__ __launch_bounds__(256) void cast_bf16_kernel(
    const float* __restrict__ in, unsigned short* __restrict__ out, int n) {
  int i = (blockIdx.x * 256 + threadIdx.x) * 4;
  if (i >= n) return;
  f32x4 v = *(const f32x4*)(in + i);
  union { unsigned short u[4]; uint2v v2; } o;
#pragma unroll
  for (int j = 0; j < 4; ++j) o.u[j] = f2bf(v[j]);
  *(uint2v*)(out + i) = o.v2;
}

// ------------- transpose + cast: in fp32 [R][C] -> out bf16 [C][R] -------------
__global__ __launch_bounds__(256) void transpose_cast_kernel(
    const float* __restrict__ in, unsigned short* __restrict__ out, int R, int C) {
  __shared__ float tile[32][33];
  const int c0 = blockIdx.x * 32, r0 = blockIdx.y * 32;
  const int tx = threadIdx.x & 31, ty = threadIdx.x >> 5;  // 32 x 8
#pragma unroll
  for (int i = 0; i < 32; i += 8)
    tile[ty + i][tx] = in[(size_t)(r0 + ty + i) * C + c0 + tx];
  __syncthreads();
#pragma unroll
  for (int i = 0; i < 32; i += 8)
    out[(size_t)(c0 + ty + i) * R + r0 + tx] = f2bf(tile[tx][ty + i]);
}

// ------------ gemm_bt64: EXACT r11 GEMM (proven 117.7 us QKV / ~39 us proj) ------------
// 256x128 tile, BK=64, 8 waves, 4Mx2N 64x64 wave tiles, double-buffered LDS (96 KB),
// counted vmcnt + raw s_barrier, stage between MFMA clusters, source-side XOR swizzle.
template <int OUT_BF16>
__global__ __launch_bounds__(512, 2) void gemm_bt64(
    const unsigned short* __restrict__ A, const unsigned short* __restrict__ Bt,
    void* __restrict__ Cout, int M, int Nn, int K) {
  __shared__ unsigned short As[2][256 * 64];  // 64 KiB
  __shared__ unsigned short Bs[2][128 * 64];  // 32 KiB
  const int t = threadIdx.x;
  const int lane = t & 63, w = t >> 6;
  const int wr = (w >> 1) * 64;
  const int wc = (w & 1) * 64;
  const int brow = blockIdx.y * 256, bcol = blockIdx.x * 128;
  const int l15 = lane & 15, lk = lane >> 4;
  const int p = l15 & 7;

  f32x4 acc[4][4] = {};

  auto stage = [&](int buf, int ktile) {
    const int koff = ktile * 64;
#pragma unroll
    for (int j = 0; j < 4; ++j) {
      const int slot = j * 512 + t;
      const int row = slot >> 3, ch = slot & 7;
      const int sc = ch ^ (row & 7);
      async_ld16(&As[buf][slot * 8], A + (size_t)(brow + row) * K + koff + sc * 8);
    }
#pragma unroll
    for (int j = 0; j < 2; ++j) {
      const int slot = j * 512 + t;
      const int row = slot >> 3, ch = slot & 7;
      const int sc = ch ^ (row & 7);
      async_ld16(&Bs[buf][slot * 8], Bt + (size_t)(bcol + row) * K + koff + sc * 8);
    }
  };

  const int NT = K / 64;
  stage(0, 0);
  stage(1, 1);

  for (int kt = 0; kt < NT; ++kt) {
    const int cur = kt & 1;
    if (kt == NT - 1) { asm volatile("s_waitcnt vmcnt(0)" ::: "memory"); }
    else              { asm volatile("s_waitcnt vmcnt(6)" ::: "memory"); }
    __builtin_amdgcn_sched_barrier(0);
    __builtin_amdgcn_s_barrier();

    short8 af0[4], af1[4], bf0[4], bf1[4];
#pragma unroll
    for (int m = 0; m < 4; ++m) {
      const int row = wr + m * 16 + l15;
      af0[m] = *(const short8*)&As[cur][row * 64 + (lk ^ p) * 8];
      af1[m] = *(const short8*)&As[cur][row * 64 + ((4 + lk) ^ p) * 8];
    }
#pragma unroll
    for (int n = 0; n < 4; ++n) {
      const int row = wc + n * 16 + l15;
      bf0[n] = *(const short8*)&Bs[cur][row * 64 + (lk ^ p) * 8];
      bf1[n] = *(const short8*)&Bs[cur][row * 64 + ((4 + lk) ^ p) * 8];
    }

    __builtin_amdgcn_s_setprio(1);
#pragma unroll
    for (int m = 0; m < 4; ++m)
#pragma unroll
      for (int n = 0; n < 4; ++n)
        acc[m][n] = __builtin_amdgcn_mfma_f32_16x16x32_bf16(af0[m], bf0[n], acc[m][n], 0, 0, 0);
    __builtin_amdgcn_s_setprio(0);

    asm volatile("s_waitcnt lgkmcnt(0)" ::: "memory");
    __builtin_amdgcn_sched_barrier(0);
    __builtin_amdgcn_s_barrier();
    if (kt + 2 < NT) stage(cur, kt + 2);

    __builtin_amdgcn_s_setprio(1);
#pragma unroll
    for (int m = 0; m < 4; ++m)
#pragma unroll
      for (int n = 0; n < 4; ++n)
        acc[m][n] = __builtin_amdgcn_mfma_f32_16x16x32_bf16(af1[m], bf1[n], acc[m][n], 0, 0, 0);
    __builtin_amdgcn_s_setprio(0);
  }

#pragma unroll
  for (int m = 0; m < 4; ++m)
#pragma unroll
    for (int n = 0; n < 4; ++n)
#pragma unroll
      for (int j = 0; j < 4; ++j) {
        const int row = brow + wr + m * 16 + lk * 4 + j;
        const int col = bcol + wc + n * 16 + l15;
        if (OUT_BF16)
          ((unsigned short*)Cout)[(size_t)row * Nn + col] = f2bf(acc[m][n][j]);
        else
          ((float*)Cout)[(size_t)row * Nn + col] = acc[m][n][j];
      }
}

// ------------ gemm_bt32: ROUND-14 experiment — BK=32 for 2 blocks/CU ------------
// Same 256x128 tile / wave partition / sync discipline as r11, but BK=32 halves LDS
// to 48 KB -> TWO blocks co-resident per CU (4 waves/SIMD): when one block drains at
// its vmcnt+barrier, the other block's waves fill the SIMDs (m114 mechanism).
// BK=32 rows have 4 chunks -> new swizzle: chunk ^= (row>>1)&3, giving banks
// {0,16,4,20,8,24,12,28} over an 8-row period = pure 2-way aliasing (free).
// Involution applied source-side (stage) and read-side (fragments).
template <int OUT_BF16>
__global__ __launch_bounds__(512, 2) void gemm_bt32(
    const unsigned short* __restrict__ A, const unsigned short* __restrict__ Bt,
    void* __restrict__ Cout, int M, int Nn, int K) {
  __shared__ unsigned short As[2][256 * 32];  // 16 KiB x2
  __shared__ unsigned short Bs[2][128 * 32];  // 8 KiB x2 -> 48 KiB total
  const int t = threadIdx.x;
  const int lane = t & 63, w = t >> 6;
  const int wr = (w >> 1) * 64;   // 4 M-groups of 64 rows
  const int wc = (w & 1) * 64;    // 2 N-groups of 64 cols
  const int brow = blockIdx.y * 256, bcol = blockIdx.x * 128;
  const int l15 = lane & 15, lk = lane >> 4;  // lk in 0..3 = chunk index

  f32x4 acc[4][4] = {};

  auto stage = [&](int buf, int ktile) {
    const int koff = ktile * 32;
#pragma unroll
    for (int j = 0; j < 2; ++j) {   // A: 256x32 = 1024 chunks, 2/thread
      const int slot = j * 512 + t;
      const int row = slot >> 2, ch = slot & 3;
      const int sc = ch ^ ((row >> 1) & 3);
      async_ld16(&As[buf][slot * 8], A + (size_t)(brow + row) * K + koff + sc * 8);
    }
    {                                // B: 128x32 = 512 chunks, 1/thread
      const int slot = t;
      const int row = slot >> 2, ch = slot & 3;
      const int sc = ch ^ ((row >> 1) & 3);
      async_ld16(&Bs[buf][slot * 8], Bt + (size_t)(bcol + row) * K + koff + sc * 8);
    }
  };

  const int NT = K / 32;
  stage(0, 0);
  stage(1, 1);

  for (int kt = 0; kt < NT; ++kt) {
    const int cur = kt & 1;
    if (kt == NT - 1) { asm volatile("s_waitcnt vmcnt(0)" ::: "memory"); }
    else              { asm volatile("s_waitcnt vmcnt(3)" ::: "memory"); }
    __builtin_amdgcn_sched_barrier(0);
    __builtin_amdgcn_s_barrier();

    short8 af0[4], bf0[4];
#pragma unroll
    for (int m = 0; m < 4; ++m) {
      const int row = wr + m * 16 + l15;
      af0[m] = *(const short8*)&As[cur][row * 32 + (lk ^ ((row >> 1) & 3)) * 8];
    }
#pragma unroll
    for (int n = 0; n < 4; ++n) {
      const int row = wc + n * 16 + l15;
      bf0[n] = *(const short8*)&Bs[cur][row * 32 + (lk ^ ((row >> 1) & 3)) * 8];
    }

    __builtin_amdgcn_s_setprio(1);
#pragma unroll
    for (int m = 0; m < 4; ++m)
#pragma unroll
      for (int n = 0; n < 4; ++n)
        acc[m][n] = __builtin_amdgcn_mfma_f32_16x16x32_bf16(af0[m], bf0[n], acc[m][n], 0, 0, 0);
    __builtin_amdgcn_s_setprio(0);

    asm volatile("s_waitcnt lgkmcnt(0)" ::: "memory");
    __builtin_amdgcn_sched_barrier(0);
    __builtin_amdgcn_s_barrier();
    if (kt + 2 < NT) stage(cur, kt + 2);
  }

#pragma unroll
  for (int m = 0; m < 4; ++m)
#pragma unroll
    for (int n = 0; n < 4; ++n)
#pragma unroll
      for (int j = 0; j < 4; ++j) {
        const int row = brow + wr + m * 16 + lk * 4 + j;  // D: row=(lane>>4)*4+reg
        const int col = bcol + wc + n * 16 + l15;         //    col=lane&15
        if (OUT_BF16)
          ((unsigned short*)Cout)[(size_t)row * Nn + col] = f2bf(acc[m][n][j]);
        else
          ((float*)Cout)[(size_t)row * Nn + col] = acc[m][n][j];
      }
}

// ------------- RoPE + pack: Y bf16 [B*N][6144] -> Qb,Kb [B,H,N,128], Vt [B,H,128,N] -------------
#define QSCALE 0.12751743f
__global__ __launch_bounds__(256) void rope_pack(
    const unsigned short* __restrict__ Y, const int* __restrict__ pos,
    unsigned short* __restrict__ Qb, unsigned short* __restrict__ Kb,
    unsigned short* __restrict__ Vt, int N) {
  __shared__ unsigned short vt[128 * 32];
  const int bh = blockIdx.x, b = bh >> 4, h = bh & 15;
  const int n0 = blockIdx.y * 32;
  const int t = threadIdx.x;
  const int tok = t >> 3, dp0 = (t & 7) * 8;
  const int n = n0 + tok;
  const float p = (float)pos[b * N + n];
  const size_t yb = (size_t)(b * N + n) * 6144 + h * 128;

  ushort8 qlo = *(const ushort8*)&Y[yb + dp0];
  ushort8 qhi = *(const ushort8*)&Y[yb + dp0 + 64];
  ushort8 klo = *(const ushort8*)&Y[yb + 2048 + dp0];
  ushort8 khi = *(const ushort8*)&Y[yb + 2048 + dp0 + 64];
  ushort8 vlo = *(const ushort8*)&Y[yb + 4096 + dp0];
  ushort8 vhi = *(const ushort8*)&Y[yb + 4096 + dp0 + 64];

  ushort8 oql, oqh, okl, okh;
#pragma unroll
  for (int i = 0; i < 8; ++i) {
    const float d = (float)(dp0 + i);
    const float ang = p * exp2f(d * -0.2076205059304601f);
    const float s = sinf(ang), c = cosf(ang);
    const float ql = bf2f(qlo[i]), qh = bf2f(qhi[i]);
    const float kl = bf2f(klo[i]), kh = bf2f(khi[i]);
    oql[i] = f2bf((ql * c - qh * s) * QSCALE);
    oqh[i] = f2bf((qh * c + ql * s) * QSCALE);
    okl[i] = f2bf(kl * c - kh * s);
    okh[i] = f2bf(kh * c + kl * s);
    vt[(dp0 + i) * 32 + tok] = vlo[i];
    vt[(dp0 + 64 + i) * 32 + tok] = vhi[i];
  }
  const size_t qb = ((size_t)bh * N + n) * 128;
  *(ushort8*)&Qb[qb + dp0] = oql;
  *(ushort8*)&Qb[qb + dp0 + 64] = oqh;
  *(ushort8*)&Kb[qb + dp0] = okl;
  *(ushort8*)&Kb[qb + dp0 + 64] = okh;
  __syncthreads();
  const int d = t >> 1, half = t & 1;
  const size_t vdst = (size_t)bh * 128 * N + (size_t)d * N + n0 + half * 16;
  *(ushort8*)&Vt[vdst]     = *(const ushort8*)&vt[d * 32 + half * 16];
  *(ushort8*)&Vt[vdst + 8] = *(const ushort8*)&vt[d * 32 + half * 16 + 8];
}

// ------------- causal flash attention: 4 waves/block, CU-paired chunks (r13) -------------
__global__ __launch_bounds__(256, 2) void flash_attn4(
    const unsigned short* __restrict__ Qb, const unsigned short* __restrict__ Kb,
    const unsigned short* __restrict__ Vt, unsigned short* __restrict__ Ao, int N) {
  __shared__ unsigned short Ks[2][32 * 128];   // [kv][d], 8 KiB each
  __shared__ unsigned short Vs[2][128 * 32];   // [d][kv], 8 KiB each
  const int t = threadIdx.x, lane = t & 63, w = t >> 6;          // 4 waves
  const int bh = blockIdx.x, b = bh >> 4, h = bh & 15;
  const int y = blockIdx.y;
  const int cc = (y < 8) ? (15 - y) : (y - 8);   // heavy chunks first; y,y+8 sum to 15
  const int q0 = cc * 128 + w * 32;
  const int l31 = lane & 31, hi = lane >> 5;
  const size_t base = (size_t)bh * N * 128;
  const size_t vbase = (size_t)bh * 128 * N;
  const int Twave = 4 * cc + w;     // last tile this wave needs
  const int Tblk = 4 * cc + 4;      // block sweep length

  auto stage = [&](int tt, int buf) {
    const int kv0 = tt * 32;
#pragma unroll
    for (int j = 0; j < 2; ++j) {
      const int slot = j * 256 + t;
      const int krow = slot >> 4, kch = (slot & 15) ^ (krow & 7);
      async_ld16(&Ks[buf][slot * 8], Kb + base + (size_t)(kv0 + krow) * 128 + kch * 8);
    }
#pragma unroll
    for (int j = 0; j < 2; ++j) {
      const int slot = j * 256 + t;
      const int vrow = slot >> 2, vch = (slot & 3) ^ (vrow & 3);
      async_ld16(&Vs[buf][slot * 8], Vt + vbase + (size_t)vrow * N + kv0 + vch * 8);
    }
  };

  short8 qf[8];
#pragma unroll
  for (int s = 0; s < 8; ++s)
    qf[s] = *(const short8*)&Qb[base + (size_t)(q0 + l31) * 128 + s * 16 + hi * 8];

  f32x16 acc0 = {}, acc1 = {}, acc2 = {}, acc3 = {};
  float m_run = -1e30f, l_run = 0.f;

  stage(0, 0);
  stage(1, 1);

  for (int tt = 0; tt < Tblk; ++tt) {
    const int cur = tt & 1;
    if (tt < Tblk - 1) { asm volatile("s_waitcnt vmcnt(4)" ::: "memory"); }
    else               { asm volatile("s_waitcnt vmcnt(0)" ::: "memory"); }
    __builtin_amdgcn_sched_barrier(0);
    __builtin_amdgcn_s_barrier();

    if (tt <= Twave) {
      const int kv0 = tt * 32;
      const bool masked = (tt == Twave);

      short8 kf[8];
#pragma unroll
      for (int s = 0; s < 8; ++s)
        kf[s] = *(const short8*)&Ks[cur][l31 * 128 + ((2 * s + hi) ^ (l31 & 7)) * 8];
      short8 vf[8];
#pragma unroll
      for (int c2 = 0; c2 < 2; ++c2)
#pragma unroll
        for (int dblk = 0; dblk < 4; ++dblk) {
          const int row = dblk * 32 + l31;
          vf[c2 * 4 + dblk] = *(const short8*)&Vs[cur][row * 32 + ((2 * c2 + hi) ^ (row & 3)) * 8];
        }

      f32x16 st = {};
      __builtin_amdgcn_s_setprio(1);
#pragma unroll
      for (int s = 0; s < 8; ++s)
        st = __builtin_amdgcn_mfma_f32_32x32x16_bf16(kf[s], qf[s], st, 0, 0, 0);
      __builtin_amdgcn_s_setprio(0);

      if (masked) {
        const int qg = q0 + l31;
#pragma unroll
        for (int r = 0; r < 16; ++r) {
          const int kvg = kv0 + (r & 3) + 8 * ((r >> 2) & 1) + 16 * (r >> 3) + 4 * hi;
          st[r] = (kvg > qg) ? -1e30f : st[r];
        }
      }
      float a0 = fmaxf(st[0], st[1]),  a1 = fmaxf(st[2], st[3]),
            a2 = fmaxf(st[4], st[5]),  a3 = fmaxf(st[6], st[7]),
            a4 = fmaxf(st[8], st[9]),  a5 = fmaxf(st[10], st[11]),
            a6 = fmaxf(st[12], st[13]), a7 = fmaxf(st[14], st[15]);
      a0 = fmaxf(a0, a1); a2 = fmaxf(a2, a3); a4 = fmaxf(a4, a5); a6 = fmaxf(a6, a7);
      a0 = fmaxf(a0, a2); a4 = fmaxf(a4, a6);
      float mt = fmaxf(a0, a4);
      mt = fmaxf(mt, __shfl_xor(mt, 32));

      float m_new = fmaxf(m_run, mt);
      const bool defer = __all(mt - m_run <= 8.f);  // T13
      if (defer) {
        m_new = m_run;
      } else {
        const float alpha = exp2_fast(m_run - m_new);
        l_run *= alpha;
#pragma unroll
        for (int r = 0; r < 16; ++r) {
          acc0[r] *= alpha; acc1[r] *= alpha; acc2[r] *= alpha; acc3[r] *= alpha;
        }
      }
      m_run = m_new;

#pragma unroll
      for (int r = 0; r < 16; ++r) st[r] = exp2_fast(st[r] - m_new);
      float s0 = (st[0] + st[1]) + (st[2] + st[3]), s1 = (st[4] + st[5]) + (st[6] + st[7]);
      float s2 = (st[8] + st[9]) + (st[10] + st[11]), s3 = (st[12] + st[13]) + (st[14] + st[15]);
      float lsum = (s0 + s1) + (s2 + s3);
      lsum += __shfl_xor(lsum, 32);
      l_run += lsum;

      short8 pB0, pB1;
#pragma unroll
      for (int c2 = 0; c2 < 2; ++c2) {
        const int o = c2 * 8;
        const uint32_t P01 = cvt_pk_bf16(st[o + 0], st[o + 1]);
        const uint32_t P23 = cvt_pk_bf16(st[o + 2], st[o + 3]);
        const uint32_t P45 = cvt_pk_bf16(st[o + 4], st[o + 5]);
        const uint32_t P67 = cvt_pk_bf16(st[o + 6], st[o + 7]);
        const uint32_t S01 = (uint32_t)__shfl_xor((int)P01, 32);
        const uint32_t S23 = (uint32_t)__shfl_xor((int)P23, 32);
        const uint32_t S45 = (uint32_t)__shfl_xor((int)P45, 32);
        const uint32_t S67 = (uint32_t)__shfl_xor((int)P67, 32);
        union { uint32_t ww[4]; short8 s8; } u;
        u.ww[0] = hi ? S45 : P01;
        u.ww[1] = hi ? S67 : P23;
        u.ww[2] = hi ? P45 : S01;
        u.ww[3] = hi ? P67 : S23;
        if (c2 == 0) pB0 = u.s8; else pB1 = u.s8;
      }

      __builtin_amdgcn_s_setprio(1);
      acc0 = __builtin_amdgcn_mfma_f32_32x32x16_bf16(vf[0], pB0, acc0, 0, 0, 0);
      acc1 = __builtin_amdgcn_mfma_f32_32x32x16_bf16(vf[1], pB0, acc1, 0, 0, 0);
      acc2 = __builtin_amdgcn_mfma_f32_32x32x16_bf16(vf[2], pB0, acc2, 0, 0, 0);
      acc3 = __builtin_amdgcn_mfma_f32_32x32x16_bf16(vf[3], pB0, acc3, 0, 0, 0);
      acc0 = __builtin_amdgcn_mfma_f32_32x32x16_bf16(vf[4], pB1, acc0, 0, 0, 0);
      acc1 = __builtin_amdgcn_mfma_f32_32x32x16_bf16(vf[5], pB1, acc1, 0, 0, 0);
      acc2 = __builtin_amdgcn_mfma_f32_32x32x16_bf16(vf[6], pB1, acc2, 0, 0, 0);
      acc3 = __builtin_amdgcn_mfma_f32_32x32x16_bf16(vf[7], pB1, acc3, 0, 0, 0);
      __builtin_amdgcn_s_setprio(0);
    }

    asm volatile("s_waitcnt lgkmcnt(0)" ::: "memory");
    __builtin_amdgcn_sched_barrier(0);
    __builtin_amdgcn_s_barrier();
    if (tt + 2 < Tblk) stage(tt + 2, cur);
  }

  const float inv = 1.f / l_run;
  const size_t orow = (size_t)(b * N + q0 + l31) * 2048 + h * 128;
#pragma unroll
  for (int r = 0; r < 16; r += 2) {
    const int doff = (r & 3) + 8 * ((r >> 2) & 1) + 16 * (r >> 3) + 4 * hi;
    *(uint32_t*)&Ao[orow + 0  + doff] = cvt_pk_bf16(acc0[r] * inv, acc0[r + 1] * inv);
    *(uint32_t*)&Ao[orow + 32 + doff] = cvt_pk_bf16(acc1[r] * inv, acc1[r + 1] * inv);
    *(uint32_t*)&Ao[orow + 64 + doff] = cvt_pk_bf16(acc2[r] * inv, acc2[r + 1] * inv);
    *(uint32_t*)&Ao[orow + 96 + doff] = cvt_pk_bf16(acc3[r] * inv, acc3[r + 1] * inv);
  }
}

extern "C" void kernel_launch(void* const* d_in, const int* in_sizes, int n_in,
                              void* d_out, int out_size, void* d_ws, size_t ws_size,
                              hipStream_t stream) {
  const float* x      = (const float*)d_in[0];
  const int*   pos    = (const int*)d_in[1];
  const float* Wqkv   = (const float*)d_in[2];
  const float* Wproj  = (const float*)d_in[3];
  float* out = (float*)d_out;

  const int N = 2048, C = 2048;
  const int M = 2 * N;

  char* ws = (char*)d_ws;
  unsigned short* Xb      = (unsigned short*)(ws + 0);            // 16 MiB, reused as Ao
  unsigned short* Wqkv_t  = (unsigned short*)(ws + 16777216);     // 24 MiB
  unsigned short* Wproj_t = (unsigned short*)(ws + 41943040);     // 8 MiB
  unsigned short* Y       = (unsigned short*)(ws + 50331648);     // 48 MiB
  unsigned short* Qb      = (unsigned short*)(ws + 100663296);    // 16 MiB
  unsigned short* Kb      = (unsigned short*)(ws + 117440512);    // 16 MiB
  unsigned short* Vt      = (unsigned short*)(ws + 134217728);    // 16 MiB
  unsigned short* Ao = Xb;

  cast_bf16_kernel<<<(M * C) / 1024, 256, 0, stream>>>(x, Xb, M * C);
  transpose_cast_kernel<<<dim3(3 * C / 32, C / 32), 256, 0, stream>>>(Wqkv, Wqkv_t, C, 3 * C);
  transpose_cast_kernel<<<dim3(C / 32, C / 32), 256, 0, stream>>>(Wproj, Wproj_t, C, C);
  gemm_bt32<1><<<dim3(3 * C / 128, M / 256), 512, 0, stream>>>(Xb, Wqkv_t, Y, M, 3 * C, C);
  rope_pack<<<dim3(32, N / 32), 256, 0, stream>>>(Y, pos, Qb, Kb, Vt, N);
  flash_attn4<<<dim3(32, 16), 256, 0, stream>>>(Qb, Kb, Vt, Ao, N);
  gemm_bt64<0><<<dim3(C / 128, M / 256), 512, 0, stream>>>(Ao, Wproj_t, out, M, C, C);
}

// Round 15
// 293.692 us; speedup vs baseline: 1.0211x; 1.0211x over previous
//
#include <hip/hip_runtime.h>
#include <stdint.h>

#define DEV __device__ __forceinline__

typedef __attribute__((ext_vector_type(8))) short short8;
typedef __attribute__((ext_vector_type(8))) unsigned short ushort8;
typedef __attribute__((ext_vector_type(4))) float f32x4;
typedef __attribute__((ext_vector_type(16))) float f32x16;
typedef __attribute__((ext_vector_type(2))) unsigned int uint2v;

DEV unsigned short f2bf(float f) {
  union { float f; uint32_t u; } v; v.f = f;
  uint32_t u = v.u;
  u += 0x7FFFu + ((u >> 16) & 1);  // RNE
  return (unsigned short)(u >> 16);
}
DEV float bf2f(unsigned short s) {
  union { uint32_t u; float f; } v; v.u = ((uint32_t)s) << 16;
  return v.f;
}
DEV float exp2_fast(float x) {
  float r; asm("v_exp_f32 %0, %1" : "=v"(r) : "v"(x)); return r;
}
DEV uint32_t cvt_pk_bf16(float lo, float hi) {
  uint32_t r; asm("v_cvt_pk_bf16_f32 %0, %1, %2" : "=v"(r) : "v"(lo), "v"(hi)); return r;
}

DEV void async_ld16(void* lds, const void* g) {
  __builtin_amdgcn_global_load_lds(
      (const __attribute__((address_space(1))) unsigned int*)g,
      (__attribute__((address_space(3))) unsigned int*)lds, 16, 0, 0);
}

// ---------------- cast fp32 -> bf16 (vectorized) ----------------
__global__ __launch_bounds__(256) void cast_bf16_kernel(
    const float* __restrict__ in, unsigned short* __restrict__ out, int n) {
  int i = (blockIdx.x * 256 + threadIdx.x) * 4;
  if (i >= n) return;
  f32x4 v = *(const f32x4*)(in + i);
  union { unsigned short u[4]; uint2v v2; } o;
#pragma unroll
  for (int j = 0; j < 4; ++j) o.u[j] = f2bf(v[j]);
  *(uint2v*)(out + i) = o.v2;
}

// ------------- transpose + cast: in fp32 [R][C] -> out bf16 [C][R] -------------
__global__ __launch_bounds__(256) void transpose_cast_kernel(
    const float* __restrict__ in, unsigned short* __restrict__ out, int R, int C) {
  __shared__ float tile[32][33];
  const int c0 = blockIdx.x * 32, r0 = blockIdx.y * 32;
  const int tx = threadIdx.x & 31, ty = threadIdx.x >> 5;  // 32 x 8
#pragma unroll
  for (int i = 0; i < 32; i += 8)
    tile[ty + i][tx] = in[(size_t)(r0 + ty + i) * C + c0 + tx];
  __syncthreads();
#pragma unroll
  for (int i = 0; i < 32; i += 8)
    out[(size_t)(c0 + ty + i) * R + r0 + tx] = f2bf(tile[tx][ty + i]);
}

// ------------ gemm_bt64: EXACT r11 GEMM (proven 117.7 us QKV / ~39 us proj) ------------
// 256x128 tile, BK=64, 8 waves, 4Mx2N 64x64 wave tiles, double-buffered LDS (96 KB),
// counted vmcnt + raw s_barrier, stage between MFMA clusters, source-side XOR swizzle.
template <int OUT_BF16>
__global__ __launch_bounds__(512, 2) void gemm_bt64(
    const unsigned short* __restrict__ A, const unsigned short* __restrict__ Bt,
    void* __restrict__ Cout, int M, int Nn, int K) {
  __shared__ unsigned short As[2][256 * 64];  // 64 KiB
  __shared__ unsigned short Bs[2][128 * 64];  // 32 KiB
  const int t = threadIdx.x;
  const int lane = t & 63, w = t >> 6;
  const int wr = (w >> 1) * 64;
  const int wc = (w & 1) * 64;
  const int brow = blockIdx.y * 256, bcol = blockIdx.x * 128;
  const int l15 = lane & 15, lk = lane >> 4;
  const int p = l15 & 7;

  f32x4 acc[4][4] = {};

  auto stage = [&](int buf, int ktile) {
    const int koff = ktile * 64;
#pragma unroll
    for (int j = 0; j < 4; ++j) {
      const int slot = j * 512 + t;
      const int row = slot >> 3, ch = slot & 7;
      const int sc = ch ^ (row & 7);
      async_ld16(&As[buf][slot * 8], A + (size_t)(brow + row) * K + koff + sc * 8);
    }
#pragma unroll
    for (int j = 0; j < 2; ++j) {
      const int slot = j * 512 + t;
      const int row = slot >> 3, ch = slot & 7;
      const int sc = ch ^ (row & 7);
      async_ld16(&Bs[buf][slot * 8], Bt + (size_t)(bcol + row) * K + koff + sc * 8);
    }
  };

  const int NT = K / 64;
  stage(0, 0);
  stage(1, 1);

  for (int kt = 0; kt < NT; ++kt) {
    const int cur = kt & 1;
    if (kt == NT - 1) { asm volatile("s_waitcnt vmcnt(0)" ::: "memory"); }
    else              { asm volatile("s_waitcnt vmcnt(6)" ::: "memory"); }
    __builtin_amdgcn_sched_barrier(0);
    __builtin_amdgcn_s_barrier();

    short8 af0[4], af1[4], bf0[4], bf1[4];
#pragma unroll
    for (int m = 0; m < 4; ++m) {
      const int row = wr + m * 16 + l15;
      af0[m] = *(const short8*)&As[cur][row * 64 + (lk ^ p) * 8];
      af1[m] = *(const short8*)&As[cur][row * 64 + ((4 + lk) ^ p) * 8];
    }
#pragma unroll
    for (int n = 0; n < 4; ++n) {
      const int row = wc + n * 16 + l15;
      bf0[n] = *(const short8*)&Bs[cur][row * 64 + (lk ^ p) * 8];
      bf1[n] = *(const short8*)&Bs[cur][row * 64 + ((4 + lk) ^ p) * 8];
    }

    __builtin_amdgcn_s_setprio(1);
#pragma unroll
    for (int m = 0; m < 4; ++m)
#pragma unroll
      for (int n = 0; n < 4; ++n)
        acc[m][n] = __builtin_amdgcn_mfma_f32_16x16x32_bf16(af0[m], bf0[n], acc[m][n], 0, 0, 0);
    __builtin_amdgcn_s_setprio(0);

    asm volatile("s_waitcnt lgkmcnt(0)" ::: "memory");
    __builtin_amdgcn_sched_barrier(0);
    __builtin_amdgcn_s_barrier();
    if (kt + 2 < NT) stage(cur, kt + 2);

    __builtin_amdgcn_s_setprio(1);
#pragma unroll
    for (int m = 0; m < 4; ++m)
#pragma unroll
      for (int n = 0; n < 4; ++n)
        acc[m][n] = __builtin_amdgcn_mfma_f32_16x16x32_bf16(af1[m], bf1[n], acc[m][n], 0, 0, 0);
    __builtin_amdgcn_s_setprio(0);
  }

#pragma unroll
  for (int m = 0; m < 4; ++m)
#pragma unroll
    for (int n = 0; n < 4; ++n)
#pragma unroll
      for (int j = 0; j < 4; ++j) {
        const int row = brow + wr + m * 16 + lk * 4 + j;
        const int col = bcol + wc + n * 16 + l15;
        if (OUT_BF16)
          ((unsigned short*)Cout)[(size_t)row * Nn + col] = f2bf(acc[m][n][j]);
        else
          ((float*)Cout)[(size_t)row * Nn + col] = acc[m][n][j];
      }
}

// ------------- RoPE + pack: Y bf16 [B*N][6144] -> Qb,Kb [B,H,N,128], Vt [B,H,128,N] -------------
#define QSCALE 0.12751743f
__global__ __launch_bounds__(256) void rope_pack(
    const unsigned short* __restrict__ Y, const int* __restrict__ pos,
    unsigned short* __restrict__ Qb, unsigned short* __restrict__ Kb,
    unsigned short* __restrict__ Vt, int N) {
  __shared__ unsigned short vt[128 * 32];
  const int bh = blockIdx.x, b = bh >> 4, h = bh & 15;
  const int n0 = blockIdx.y * 32;
  const int t = threadIdx.x;
  const int tok = t >> 3, dp0 = (t & 7) * 8;
  const int n = n0 + tok;
  const float p = (float)pos[b * N + n];
  const size_t yb = (size_t)(b * N + n) * 6144 + h * 128;

  ushort8 qlo = *(const ushort8*)&Y[yb + dp0];
  ushort8 qhi = *(const ushort8*)&Y[yb + dp0 + 64];
  ushort8 klo = *(const ushort8*)&Y[yb + 2048 + dp0];
  ushort8 khi = *(const ushort8*)&Y[yb + 2048 + dp0 + 64];
  ushort8 vlo = *(const ushort8*)&Y[yb + 4096 + dp0];
  ushort8 vhi = *(const ushort8*)&Y[yb + 4096 + dp0 + 64];

  ushort8 oql, oqh, okl, okh;
#pragma unroll
  for (int i = 0; i < 8; ++i) {
    const float d = (float)(dp0 + i);
    const float ang = p * exp2f(d * -0.2076205059304601f);
    const float s = sinf(ang), c = cosf(ang);
    const float ql = bf2f(qlo[i]), qh = bf2f(qhi[i]);
    const float kl = bf2f(klo[i]), kh = bf2f(khi[i]);
    oql[i] = f2bf((ql * c - qh * s) * QSCALE);
    oqh[i] = f2bf((qh * c + ql * s) * QSCALE);
    okl[i] = f2bf(kl * c - kh * s);
    okh[i] = f2bf(kh * c + kl * s);
    vt[(dp0 + i) * 32 + tok] = vlo[i];
    vt[(dp0 + 64 + i) * 32 + tok] = vhi[i];
  }
  const size_t qb = ((size_t)bh * N + n) * 128;
  *(ushort8*)&Qb[qb + dp0] = oql;
  *(ushort8*)&Qb[qb + dp0 + 64] = oqh;
  *(ushort8*)&Kb[qb + dp0] = okl;
  *(ushort8*)&Kb[qb + dp0 + 64] = okh;
  __syncthreads();
  const int d = t >> 1, half = t & 1;
  const size_t vdst = (size_t)bh * 128 * N + (size_t)d * N + n0 + half * 16;
  *(ushort8*)&Vt[vdst]     = *(const ushort8*)&vt[d * 32 + half * 16];
  *(ushort8*)&Vt[vdst + 8] = *(const ushort8*)&vt[d * 32 + half * 16 + 8];
}

// ------------- causal flash attention: 4 waves/block, CU-paired chunks (r13) -------------
__global__ __launch_bounds__(256, 2) void flash_attn4(
    const unsigned short* __restrict__ Qb, const unsigned short* __restrict__ Kb,
    const unsigned short* __restrict__ Vt, unsigned short* __restrict__ Ao, int N) {
  __shared__ unsigned short Ks[2][32 * 128];   // [kv][d], 8 KiB each
  __shared__ unsigned short Vs[2][128 * 32];   // [d][kv], 8 KiB each
  const int t = threadIdx.x, lane = t & 63, w = t >> 6;          // 4 waves
  const int bh = blockIdx.x, b = bh >> 4, h = bh & 15;
  const int y = blockIdx.y;
  const int cc = (y < 8) ? (15 - y) : (y - 8);   // heavy chunks first; y,y+8 sum to 15
  const int q0 = cc * 128 + w * 32;
  const int l31 = lane & 31, hi = lane >> 5;
  const size_t base = (size_t)bh * N * 128;
  const size_t vbase = (size_t)bh * 128 * N;
  const int Twave = 4 * cc + w;     // last tile this wave needs
  const int Tblk = 4 * cc + 4;      // block sweep length

  auto stage = [&](int tt, int buf) {
    const int kv0 = tt * 32;
#pragma unroll
    for (int j = 0; j < 2; ++j) {
      const int slot = j * 256 + t;
      const int krow = slot >> 4, kch = (slot & 15) ^ (krow & 7);
      async_ld16(&Ks[buf][slot * 8], Kb + base + (size_t)(kv0 + krow) * 128 + kch * 8);
    }
#pragma unroll
    for (int j = 0; j < 2; ++j) {
      const int slot = j * 256 + t;
      const int vrow = slot >> 2, vch = (slot & 3) ^ (vrow & 3);
      async_ld16(&Vs[buf][slot * 8], Vt + vbase + (size_t)vrow * N + kv0 + vch * 8);
    }
  };

  short8 qf[8];
#pragma unroll
  for (int s = 0; s < 8; ++s)
    qf[s] = *(const short8*)&Qb[base + (size_t)(q0 + l31) * 128 + s * 16 + hi * 8];

  f32x16 acc0 = {}, acc1 = {}, acc2 = {}, acc3 = {};
  float m_run = -1e30f, l_run = 0.f;

  stage(0, 0);
  stage(1, 1);

  for (int tt = 0; tt < Tblk; ++tt) {
    const int cur = tt & 1;
    if (tt < Tblk - 1) { asm volatile("s_waitcnt vmcnt(4)" ::: "memory"); }
    else               { asm volatile("s_waitcnt vmcnt(0)" ::: "memory"); }
    __builtin_amdgcn_sched_barrier(0);
    __builtin_amdgcn_s_barrier();

    if (tt <= Twave) {
      const int kv0 = tt * 32;
      const bool masked = (tt == Twave);

      short8 kf[8];
#pragma unroll
      for (int s = 0; s < 8; ++s)
        kf[s] = *(const short8*)&Ks[cur][l31 * 128 + ((2 * s + hi) ^ (l31 & 7)) * 8];
      short8 vf[8];
#pragma unroll
      for (int c2 = 0; c2 < 2; ++c2)
#pragma unroll
        for (int dblk = 0; dblk < 4; ++dblk) {
          const int row = dblk * 32 + l31;
          vf[c2 * 4 + dblk] = *(const short8*)&Vs[cur][row * 32 + ((2 * c2 + hi) ^ (row & 3)) * 8];
        }

      f32x16 st = {};
      __builtin_amdgcn_s_setprio(1);
#pragma unroll
      for (int s = 0; s < 8; ++s)
        st = __builtin_amdgcn_mfma_f32_32x32x16_bf16(kf[s], qf[s], st, 0, 0, 0);
      __builtin_amdgcn_s_setprio(0);

      if (masked) {
        const int qg = q0 + l31;
#pragma unroll
        for (int r = 0; r < 16; ++r) {
          const int kvg = kv0 + (r & 3) + 8 * ((r >> 2) & 1) + 16 * (r >> 3) + 4 * hi;
          st[r] = (kvg > qg) ? -1e30f : st[r];
        }
      }
      float a0 = fmaxf(st[0], st[1]),  a1 = fmaxf(st[2], st[3]),
            a2 = fmaxf(st[4], st[5]),  a3 = fmaxf(st[6], st[7]),
            a4 = fmaxf(st[8], st[9]),  a5 = fmaxf(st[10], st[11]),
            a6 = fmaxf(st[12], st[13]), a7 = fmaxf(st[14], st[15]);
      a0 = fmaxf(a0, a1); a2 = fmaxf(a2, a3); a4 = fmaxf(a4, a5); a6 = fmaxf(a6, a7);
      a0 = fmaxf(a0, a2); a4 = fmaxf(a4, a6);
      float mt = fmaxf(a0, a4);
      mt = fmaxf(mt, __shfl_xor(mt, 32));

      float m_new = fmaxf(m_run, mt);
      const bool defer = __all(mt - m_run <= 8.f);  // T13
      if (defer) {
        m_new = m_run;
      } else {
        const float alpha = exp2_fast(m_run - m_new);
        l_run *= alpha;
#pragma unroll
        for (int r = 0; r < 16; ++r) {
          acc0[r] *= alpha; acc1[r] *= alpha; acc2[r] *= alpha; acc3[r] *= alpha;
        }
      }
      m_run = m_new;

#pragma unroll
      for (int r = 0; r < 16; ++r) st[r] = exp2_fast(st[r] - m_new);
      float s0 = (st[0] + st[1]) + (st[2] + st[3]), s1 = (st[4] + st[5]) + (st[6] + st[7]);
      float s2 = (st[8] + st[9]) + (st[10] + st[11]), s3 = (st[12] + st[13]) + (st[14] + st[15]);
      float lsum = (s0 + s1) + (s2 + s3);
      lsum += __shfl_xor(lsum, 32);
      l_run += lsum;

      short8 pB0, pB1;
#pragma unroll
      for (int c2 = 0; c2 < 2; ++c2) {
        const int o = c2 * 8;
        const uint32_t P01 = cvt_pk_bf16(st[o + 0], st[o + 1]);
        const uint32_t P23 = cvt_pk_bf16(st[o + 2], st[o + 3]);
        const uint32_t P45 = cvt_pk_bf16(st[o + 4], st[o + 5]);
        const uint32_t P67 = cvt_pk_bf16(st[o + 6], st[o + 7]);
        const uint32_t S01 = (uint32_t)__shfl_xor((int)P01, 32);
        const uint32_t S23 = (uint32_t)__shfl_xor((int)P23, 32);
        const uint32_t S45 = (uint32_t)__shfl_xor((int)P45, 32);
        const uint32_t S67 = (uint32_t)__shfl_xor((int)P67, 32);
        union { uint32_t ww[4]; short8 s8; } u;
        u.ww[0] = hi ? S45 : P01;
        u.ww[1] = hi ? S67 : P23;
        u.ww[2] = hi ? P45 : S01;
        u.ww[3] = hi ? P67 : S23;
        if (c2 == 0) pB0 = u.s8; else pB1 = u.s8;
      }

      __builtin_amdgcn_s_setprio(1);
      acc0 = __builtin_amdgcn_mfma_f32_32x32x16_bf16(vf[0], pB0, acc0, 0, 0, 0);
      acc1 = __builtin_amdgcn_mfma_f32_32x32x16_bf16(vf[1], pB0, acc1, 0, 0, 0);
      acc2 = __builtin_amdgcn_mfma_f32_32x32x16_bf16(vf[2], pB0, acc2, 0, 0, 0);
      acc3 = __builtin_amdgcn_mfma_f32_32x32x16_bf16(vf[3], pB0, acc3, 0, 0, 0);
      acc0 = __builtin_amdgcn_mfma_f32_32x32x16_bf16(vf[4], pB1, acc0, 0, 0, 0);
      acc1 = __builtin_amdgcn_mfma_f32_32x32x16_bf16(vf[5], pB1, acc1, 0, 0, 0);
      acc2 = __builtin_amdgcn_mfma_f32_32x32x16_bf16(vf[6], pB1, acc2, 0, 0, 0);
      acc3 = __builtin_amdgcn_mfma_f32_32x32x16_bf16(vf[7], pB1, acc3, 0, 0, 0);
      __builtin_amdgcn_s_setprio(0);
    }

    asm volatile("s_waitcnt lgkmcnt(0)" ::: "memory");
    __builtin_amdgcn_sched_barrier(0);
    __builtin_amdgcn_s_barrier();
    if (tt + 2 < Tblk) stage(tt + 2, cur);
  }

  const float inv = 1.f / l_run;
  const size_t orow = (size_t)(b * N + q0 + l31) * 2048 + h * 128;
#pragma unroll
  for (int r = 0; r < 16; r += 2) {
    const int doff = (r & 3) + 8 * ((r >> 2) & 1) + 16 * (r >> 3) + 4 * hi;
    *(uint32_t*)&Ao[orow + 0  + doff] = cvt_pk_bf16(acc0[r] * inv, acc0[r + 1] * inv);
    *(uint32_t*)&Ao[orow + 32 + doff] = cvt_pk_bf16(acc1[r] * inv, acc1[r + 1] * inv);
    *(uint32_t*)&Ao[orow + 64 + doff] = cvt_pk_bf16(acc2[r] * inv, acc2[r + 1] * inv);
    *(uint32_t*)&Ao[orow + 96 + doff] = cvt_pk_bf16(acc3[r] * inv, acc3[r + 1] * inv);
  }
}

extern "C" void kernel_launch(void* const* d_in, const int* in_sizes, int n_in,
                              void* d_out, int out_size, void* d_ws, size_t ws_size,
                              hipStream_t stream) {
  const float* x      = (const float*)d_in[0];
  const int*   pos    = (const int*)d_in[1];
  const float* Wqkv   = (const float*)d_in[2];
  const float* Wproj  = (const float*)d_in[3];
  float* out = (float*)d_out;

  const int N = 2048, C = 2048;
  const int M = 2 * N;

  char* ws = (char*)d_ws;
  unsigned short* Xb      = (unsigned short*)(ws + 0);            // 16 MiB, reused as Ao
  unsigned short* Wqkv_t  = (unsigned short*)(ws + 16777216);     // 24 MiB
  unsigned short* Wproj_t = (unsigned short*)(ws + 41943040);     // 8 MiB
  unsigned short* Y       = (unsigned short*)(ws + 50331648);     // 48 MiB
  unsigned short* Qb      = (unsigned short*)(ws + 100663296);    // 16 MiB
  unsigned short* Kb      = (unsigned short*)(ws + 117440512);    // 16 MiB
  unsigned short* Vt      = (unsigned short*)(ws + 134217728);    // 16 MiB
  unsigned short* Ao = Xb;

  cast_bf16_kernel<<<(M * C) / 1024, 256, 0, stream>>>(x, Xb, M * C);
  transpose_cast_kernel<<<dim3(3 * C / 32, C / 32), 256, 0, stream>>>(Wqkv, Wqkv_t, C, 3 * C);
  transpose_cast_kernel<<<dim3(C / 32, C / 32), 256, 0, stream>>>(Wproj, Wproj_t, C, C);
  gemm_bt64<1><<<dim3(3 * C / 128, M / 256), 512, 0, stream>>>(Xb, Wqkv_t, Y, M, 3 * C, C);
  rope_pack<<<dim3(32, N / 32), 256, 0, stream>>>(Y, pos, Qb, Kb, Vt, N);
  flash_attn4<<<dim3(32, 16), 256, 0, stream>>>(Qb, Kb, Vt, Ao, N);
  gemm_bt64<0><<<dim3(C / 128, M / 256), 512, 0, stream>>>(Ao, Wproj_t, out, M, C, C);
}

// Round 16
// 265.397 us; speedup vs baseline: 1.1300x; 1.1066x over previous
//
#include <hip/hip_runtime.h>
#include <stdint.h>

#define DEV __device__ __forceinline__

typedef __attribute__((ext_vector_type(8))) short short8;
typedef __attribute__((ext_vector_type(8))) unsigned short ushort8;
typedef __attribute__((ext_vector_type(4))) float f32x4;
typedef __attribute__((ext_vector_type(16))) float f32x16;
typedef __attribute__((ext_vector_type(2))) unsigned int uint2v;

DEV unsigned short f2bf(float f) {
  union { float f; uint32_t u; } v; v.f = f;
  uint32_t u = v.u;
  u += 0x7FFFu + ((u >> 16) & 1);  // RNE
  return (unsigned short)(u >> 16);
}
DEV float bf2f(unsigned short s) {
  union { uint32_t u; float f; } v; v.u = ((uint32_t)s) << 16;
  return v.f;
}
DEV float exp2_fast(float x) {
  float r; asm("v_exp_f32 %0, %1" : "=v"(r) : "v"(x)); return r;
}
DEV uint32_t cvt_pk_bf16(float lo, float hi) {
  uint32_t r; asm("v_cvt_pk_bf16_f32 %0, %1, %2" : "=v"(r) : "v"(lo), "v"(hi)); return r;
}

DEV void async_ld16(void* lds, const void* g) {
  __builtin_amdgcn_global_load_lds(
      (const __attribute__((address_space(1))) unsigned int*)g,
      (__attribute__((address_space(3))) unsigned int*)lds, 16, 0, 0);
}

#define QSCALE 0.12751743f

// ---------------- cast fp32 -> bf16 (vectorized) ----------------
__global__ __launch_bounds__(256) void cast_bf16_kernel(
    const float* __restrict__ in, unsigned short* __restrict__ out, int n) {
  int i = (blockIdx.x * 256 + threadIdx.x) * 4;
  if (i >= n) return;
  f32x4 v = *(const f32x4*)(in + i);
  union { unsigned short u[4]; uint2v v2; } o;
#pragma unroll
  for (int j = 0; j < 4; ++j) o.u[j] = f2bf(v[j]);
  *(uint2v*)(out + i) = o.v2;
}

// ------------- transpose + cast: in fp32 [R][C] -> out bf16 [C][R] -------------
__global__ __launch_bounds__(256) void transpose_cast_kernel(
    const float* __restrict__ in, unsigned short* __restrict__ out, int R, int C) {
  __shared__ float tile[32][33];
  const int c0 = blockIdx.x * 32, r0 = blockIdx.y * 32;
  const int tx = threadIdx.x & 31, ty = threadIdx.x >> 5;  // 32 x 8
#pragma unroll
  for (int i = 0; i < 32; i += 8)
    tile[ty + i][tx] = in[(size_t)(r0 + ty + i) * C + c0 + tx];
  __syncthreads();
#pragma unroll
  for (int i = 0; i < 32; i += 8)
    out[(size_t)(c0 + ty + i) * R + r0 + tx] = f2bf(tile[tx][ty + i]);
}

// ------------- rope tables: cosT/sinT [2048][64] fp32 -------------
__global__ __launch_bounds__(256) void rope_table(
    float* __restrict__ cosT, float* __restrict__ sinT) {
  const int i = blockIdx.x * 256 + threadIdx.x;  // 131072 total
  const int n = i >> 6, d = i & 63;
  const float ang = (float)n * exp2f((float)d * -0.2076205059304601f);
  cosT[i] = cosf(ang);
  sinT[i] = sinf(ang);
}

// ------------ gemm_bt64: EXACT r11 GEMM (proj: ~39 us) ------------
template <int OUT_BF16>
__global__ __launch_bounds__(512, 2) void gemm_bt64(
    const unsigned short* __restrict__ A, const unsigned short* __restrict__ Bt,
    void* __restrict__ Cout, int M, int Nn, int K) {
  __shared__ unsigned short As[2][256 * 64];  // 64 KiB
  __shared__ unsigned short Bs[2][128 * 64];  // 32 KiB
  const int t = threadIdx.x;
  const int lane = t & 63, w = t >> 6;
  const int wr = (w >> 1) * 64;
  const int wc = (w & 1) * 64;
  const int brow = blockIdx.y * 256, bcol = blockIdx.x * 128;
  const int l15 = lane & 15, lk = lane >> 4;
  const int p = l15 & 7;

  f32x4 acc[4][4] = {};

  auto stage = [&](int buf, int ktile) {
    const int koff = ktile * 64;
#pragma unroll
    for (int j = 0; j < 4; ++j) {
      const int slot = j * 512 + t;
      const int row = slot >> 3, ch = slot & 7;
      const int sc = ch ^ (row & 7);
      async_ld16(&As[buf][slot * 8], A + (size_t)(brow + row) * K + koff + sc * 8);
    }
#pragma unroll
    for (int j = 0; j < 2; ++j) {
      const int slot = j * 512 + t;
      const int row = slot >> 3, ch = slot & 7;
      const int sc = ch ^ (row & 7);
      async_ld16(&Bs[buf][slot * 8], Bt + (size_t)(bcol + row) * K + koff + sc * 8);
    }
  };

  const int NT = K / 64;
  stage(0, 0);
  stage(1, 1);

  for (int kt = 0; kt < NT; ++kt) {
    const int cur = kt & 1;
    if (kt == NT - 1) { asm volatile("s_waitcnt vmcnt(0)" ::: "memory"); }
    else              { asm volatile("s_waitcnt vmcnt(6)" ::: "memory"); }
    __builtin_amdgcn_sched_barrier(0);
    __builtin_amdgcn_s_barrier();

    short8 af0[4], af1[4], bf0[4], bf1[4];
#pragma unroll
    for (int m = 0; m < 4; ++m) {
      const int row = wr + m * 16 + l15;
      af0[m] = *(const short8*)&As[cur][row * 64 + (lk ^ p) * 8];
      af1[m] = *(const short8*)&As[cur][row * 64 + ((4 + lk) ^ p) * 8];
    }
#pragma unroll
    for (int n = 0; n < 4; ++n) {
      const int row = wc + n * 16 + l15;
      bf0[n] = *(const short8*)&Bs[cur][row * 64 + (lk ^ p) * 8];
      bf1[n] = *(const short8*)&Bs[cur][row * 64 + ((4 + lk) ^ p) * 8];
    }

    __builtin_amdgcn_s_setprio(1);
#pragma unroll
    for (int m = 0; m < 4; ++m)
#pragma unroll
      for (int n = 0; n < 4; ++n)
        acc[m][n] = __builtin_amdgcn_mfma_f32_16x16x32_bf16(af0[m], bf0[n], acc[m][n], 0, 0, 0);
    __builtin_amdgcn_s_setprio(0);

    asm volatile("s_waitcnt lgkmcnt(0)" ::: "memory");
    __builtin_amdgcn_sched_barrier(0);
    __builtin_amdgcn_s_barrier();
    if (kt + 2 < NT) stage(cur, kt + 2);

    __builtin_amdgcn_s_setprio(1);
#pragma unroll
    for (int m = 0; m < 4; ++m)
#pragma unroll
      for (int n = 0; n < 4; ++n)
        acc[m][n] = __builtin_amdgcn_mfma_f32_16x16x32_bf16(af1[m], bf1[n], acc[m][n], 0, 0, 0);
    __builtin_amdgcn_s_setprio(0);
  }

#pragma unroll
  for (int m = 0; m < 4; ++m)
#pragma unroll
    for (int n = 0; n < 4; ++n)
#pragma unroll
      for (int j = 0; j < 4; ++j) {
        const int row = brow + wr + m * 16 + lk * 4 + j;
        const int col = bcol + wc + n * 16 + l15;
        if (OUT_BF16)
          ((unsigned short*)Cout)[(size_t)row * Nn + col] = f2bf(acc[m][n][j]);
        else
          ((float*)Cout)[(size_t)row * Nn + col] = acc[m][n][j];
      }
}

// ------------ gemm_qkv_rope: r11 K-loop + fused RoPE/pack epilogue ------------
// Writes Qb/Kb [bh][n][128] (RoPE'd, Q pre-scaled) and Vt [bh][d][n] directly —
// eliminates the Y intermediate + rope_pack kernel (saves ~96 MB HBM traffic).
// Mode from bcol: 0=Q, 1=K (RoPE via cosT/sinT tables), 2=V (transpose).
__global__ __launch_bounds__(512, 2) void gemm_qkv_rope(
    const unsigned short* __restrict__ A, const unsigned short* __restrict__ Bt,
    const int* __restrict__ pos, const float* __restrict__ cosT,
    const float* __restrict__ sinT, unsigned short* __restrict__ Qb,
    unsigned short* __restrict__ Kb, unsigned short* __restrict__ Vt,
    int M, int Nn, int K) {
  __shared__ unsigned short smem[49152];  // 96 KiB: As[2][16384] | Bs[2][8192]
  unsigned short* As = smem;
  unsigned short* Bs = smem + 32768;
  const int t = threadIdx.x;
  const int lane = t & 63, w = t >> 6;
  const int wr = (w >> 1) * 64;
  const int wc = (w & 1) * 64;
  const int brow = blockIdx.y * 256, bcol = blockIdx.x * 128;
  const int l15 = lane & 15, lk = lane >> 4;
  const int p = l15 & 7;

  f32x4 acc[4][4] = {};

  auto stage = [&](int buf, int ktile) {
    const int koff = ktile * 64;
#pragma unroll
    for (int j = 0; j < 4; ++j) {
      const int slot = j * 512 + t;
      const int row = slot >> 3, ch = slot & 7;
      const int sc = ch ^ (row & 7);
      async_ld16(&As[buf * 16384 + slot * 8], A + (size_t)(brow + row) * K + koff + sc * 8);
    }
#pragma unroll
    for (int j = 0; j < 2; ++j) {
      const int slot = j * 512 + t;
      const int row = slot >> 3, ch = slot & 7;
      const int sc = ch ^ (row & 7);
      async_ld16(&Bs[buf * 8192 + slot * 8], Bt + (size_t)(bcol + row) * K + koff + sc * 8);
    }
  };

  const int NT = K / 64;
  stage(0, 0);
  stage(1, 1);

  for (int kt = 0; kt < NT; ++kt) {
    const int cur = kt & 1;
    if (kt == NT - 1) { asm volatile("s_waitcnt vmcnt(0)" ::: "memory"); }
    else              { asm volatile("s_waitcnt vmcnt(6)" ::: "memory"); }
    __builtin_amdgcn_sched_barrier(0);
    __builtin_amdgcn_s_barrier();

    short8 af0[4], af1[4], bf0[4], bf1[4];
#pragma unroll
    for (int m = 0; m < 4; ++m) {
      const int row = wr + m * 16 + l15;
      af0[m] = *(const short8*)&As[cur * 16384 + row * 64 + (lk ^ p) * 8];
      af1[m] = *(const short8*)&As[cur * 16384 + row * 64 + ((4 + lk) ^ p) * 8];
    }
#pragma unroll
    for (int n = 0; n < 4; ++n) {
      const int row = wc + n * 16 + l15;
      bf0[n] = *(const short8*)&Bs[cur * 8192 + row * 64 + (lk ^ p) * 8];
      bf1[n] = *(const short8*)&Bs[cur * 8192 + row * 64 + ((4 + lk) ^ p) * 8];
    }

    __builtin_amdgcn_s_setprio(1);
#pragma unroll
    for (int m = 0; m < 4; ++m)
#pragma unroll
      for (int n = 0; n < 4; ++n)
        acc[m][n] = __builtin_amdgcn_mfma_f32_16x16x32_bf16(af0[m], bf0[n], acc[m][n], 0, 0, 0);
    __builtin_amdgcn_s_setprio(0);

    asm volatile("s_waitcnt lgkmcnt(0)" ::: "memory");
    __builtin_amdgcn_sched_barrier(0);
    __builtin_amdgcn_s_barrier();
    if (kt + 2 < NT) stage(cur, kt + 2);

    __builtin_amdgcn_s_setprio(1);
#pragma unroll
    for (int m = 0; m < 4; ++m)
#pragma unroll
      for (int n = 0; n < 4; ++n)
        acc[m][n] = __builtin_amdgcn_mfma_f32_16x16x32_bf16(af1[m], bf1[n], acc[m][n], 0, 0, 0);
    __builtin_amdgcn_s_setprio(0);
  }

  __syncthreads();  // all waves done with As/Bs -> smem reusable

  const int mode = bcol >> 11;        // 0=Q, 1=K, 2=V
  const int h = (bcol >> 7) & 15;
  const int b = brow >> 11, n0 = brow & 2047;

  if (mode == 2) {
    // V: smem as [d(128)][tok(256)+8pad] -> transposed write, then coalesced store
#pragma unroll
    for (int m = 0; m < 4; ++m)
#pragma unroll
      for (int n = 0; n < 4; ++n) {
        const int d = wc + n * 16 + l15;
        const int tok = wr + m * 16 + lk * 4;
        union { unsigned short u[4]; uint2v v2; } pk;
#pragma unroll
        for (int j = 0; j < 4; ++j) pk.u[j] = f2bf(acc[m][n][j]);
        *(uint2v*)&smem[d * 264 + tok] = pk.v2;
      }
    __syncthreads();
    const size_t vbase = (size_t)(b * 16 + h) * 128 * 2048;
    const int half = t >> 5, l32 = t & 31;
#pragma unroll
    for (int pp = 0; pp < 8; ++pp) {
      const int d = pp * 16 + half;
      const int nl = l32 * 8;
      ushort8 v = *(const ushort8*)&smem[d * 264 + nl];
      *(ushort8*)&Vt[vbase + (size_t)d * 2048 + n0 + nl] = v;
    }
  } else {
    // Q/K: smem as [tok(256)][d(128)+8pad]; Q pre-scaled by QSCALE (rope is linear)
    const float sc = (mode == 0) ? QSCALE : 1.0f;
#pragma unroll
    for (int m = 0; m < 4; ++m)
#pragma unroll
      for (int n = 0; n < 4; ++n) {
        const int d = wc + n * 16 + l15;
#pragma unroll
        for (int j = 0; j < 4; ++j) {
          const int r = wr + m * 16 + lk * 4 + j;
          smem[r * 136 + d] = f2bf(acc[m][n][j] * sc);
        }
      }
    __syncthreads();
    unsigned short* dst = (mode == 0) ? Qb : Kb;
    const int d0 = (t & 7) * 8;
#pragma unroll
    for (int pass = 0; pass < 4; ++pass) {
      const int r = pass * 64 + (t >> 3);
      const int prow = brow + r;
      const int pi = pos[prow];
      const short8 lo8 = *(const short8*)&smem[r * 136 + d0];
      const short8 hi8 = *(const short8*)&smem[r * 136 + 64 + d0];
      const f32x4 c0 = *(const f32x4*)&cosT[pi * 64 + d0];
      const f32x4 c1 = *(const f32x4*)&cosT[pi * 64 + d0 + 4];
      const f32x4 s0 = *(const f32x4*)&sinT[pi * 64 + d0];
      const f32x4 s1 = *(const f32x4*)&sinT[pi * 64 + d0 + 4];
      float olo[8], ohi[8];
#pragma unroll
      for (int i = 0; i < 8; ++i) {
        const float lo = bf2f((unsigned short)lo8[i]);
        const float hi = bf2f((unsigned short)hi8[i]);
        const float c = (i < 4) ? c0[i & 3] : c1[i & 3];
        const float s = (i < 4) ? s0[i & 3] : s1[i & 3];
        olo[i] = lo * c - hi * s;
        ohi[i] = hi * c + lo * s;
      }
      union { uint32_t w4[4]; ushort8 s8; } ulo, uhi;
#pragma unroll
      for (int k = 0; k < 4; ++k) {
        ulo.w4[k] = cvt_pk_bf16(olo[2 * k], olo[2 * k + 1]);
        uhi.w4[k] = cvt_pk_bf16(ohi[2 * k], ohi[2 * k + 1]);
      }
      const size_t base = ((size_t)((prow >> 11) * 16 + h) * 2048 + (prow & 2047)) * 128;
      *(ushort8*)&dst[base + d0] = ulo.s8;
      *(ushort8*)&dst[base + 64 + d0] = uhi.s8;
    }
  }
}

// ------------- causal flash attention: 4 waves/block, CU-paired chunks (r13) -------------
__global__ __launch_bounds__(256, 2) void flash_attn4(
    const unsigned short* __restrict__ Qb, const unsigned short* __restrict__ Kb,
    const unsigned short* __restrict__ Vt, unsigned short* __restrict__ Ao, int N) {
  __shared__ unsigned short Ks[2][32 * 128];   // [kv][d], 8 KiB each
  __shared__ unsigned short Vs[2][128 * 32];   // [d][kv], 8 KiB each
  const int t = threadIdx.x, lane = t & 63, w = t >> 6;          // 4 waves
  const int bh = blockIdx.x, b = bh >> 4, h = bh & 15;
  const int y = blockIdx.y;
  const int cc = (y < 8) ? (15 - y) : (y - 8);   // heavy chunks first; y,y+8 sum to 15
  const int q0 = cc * 128 + w * 32;
  const int l31 = lane & 31, hi = lane >> 5;
  const size_t base = (size_t)bh * N * 128;
  const size_t vbase = (size_t)bh * 128 * N;
  const int Twave = 4 * cc + w;     // last tile this wave needs
  const int Tblk = 4 * cc + 4;      // block sweep length

  auto stage = [&](int tt, int buf) {
    const int kv0 = tt * 32;
#pragma unroll
    for (int j = 0; j < 2; ++j) {
      const int slot = j * 256 + t;
      const int krow = slot >> 4, kch = (slot & 15) ^ (krow & 7);
      async_ld16(&Ks[buf][slot * 8], Kb + base + (size_t)(kv0 + krow) * 128 + kch * 8);
    }
#pragma unroll
    for (int j = 0; j < 2; ++j) {
      const int slot = j * 256 + t;
      const int vrow = slot >> 2, vch = (slot & 3) ^ (vrow & 3);
      async_ld16(&Vs[buf][slot * 8], Vt + vbase + (size_t)vrow * N + kv0 + vch * 8);
    }
  };

  short8 qf[8];
#pragma unroll
  for (int s = 0; s < 8; ++s)
    qf[s] = *(const short8*)&Qb[base + (size_t)(q0 + l31) * 128 + s * 16 + hi * 8];

  f32x16 acc0 = {}, acc1 = {}, acc2 = {}, acc3 = {};
  float m_run = -1e30f, l_run = 0.f;

  stage(0, 0);
  stage(1, 1);

  for (int tt = 0; tt < Tblk; ++tt) {
    const int cur = tt & 1;
    if (tt < Tblk - 1) { asm volatile("s_waitcnt vmcnt(4)" ::: "memory"); }
    else               { asm volatile("s_waitcnt vmcnt(0)" ::: "memory"); }
    __builtin_amdgcn_sched_barrier(0);
    __builtin_amdgcn_s_barrier();

    if (tt <= Twave) {
      const int kv0 = tt * 32;
      const bool masked = (tt == Twave);

      short8 kf[8];
#pragma unroll
      for (int s = 0; s < 8; ++s)
        kf[s] = *(const short8*)&Ks[cur][l31 * 128 + ((2 * s + hi) ^ (l31 & 7)) * 8];
      short8 vf[8];
#pragma unroll
      for (int c2 = 0; c2 < 2; ++c2)
#pragma unroll
        for (int dblk = 0; dblk < 4; ++dblk) {
          const int row = dblk * 32 + l31;
          vf[c2 * 4 + dblk] = *(const short8*)&Vs[cur][row * 32 + ((2 * c2 + hi) ^ (row & 3)) * 8];
        }

      f32x16 st = {};
      __builtin_amdgcn_s_setprio(1);
#pragma unroll
      for (int s = 0; s < 8; ++s)
        st = __builtin_amdgcn_mfma_f32_32x32x16_bf16(kf[s], qf[s], st, 0, 0, 0);
      __builtin_amdgcn_s_setprio(0);

      if (masked) {
        const int qg = q0 + l31;
#pragma unroll
        for (int r = 0; r < 16; ++r) {
          const int kvg = kv0 + (r & 3) + 8 * ((r >> 2) & 1) + 16 * (r >> 3) + 4 * hi;
          st[r] = (kvg > qg) ? -1e30f : st[r];
        }
      }
      float a0 = fmaxf(st[0], st[1]),  a1 = fmaxf(st[2], st[3]),
            a2 = fmaxf(st[4], st[5]),  a3 = fmaxf(st[6], st[7]),
            a4 = fmaxf(st[8], st[9]),  a5 = fmaxf(st[10], st[11]),
            a6 = fmaxf(st[12], st[13]), a7 = fmaxf(st[14], st[15]);
      a0 = fmaxf(a0, a1); a2 = fmaxf(a2, a3); a4 = fmaxf(a4, a5); a6 = fmaxf(a6, a7);
      a0 = fmaxf(a0, a2); a4 = fmaxf(a4, a6);
      float mt = fmaxf(a0, a4);
      mt = fmaxf(mt, __shfl_xor(mt, 32));

      float m_new = fmaxf(m_run, mt);
      const bool defer = __all(mt - m_run <= 8.f);  // T13
      if (defer) {
        m_new = m_run;
      } else {
        const float alpha = exp2_fast(m_run - m_new);
        l_run *= alpha;
#pragma unroll
        for (int r = 0; r < 16; ++r) {
          acc0[r] *= alpha; acc1[r] *= alpha; acc2[r] *= alpha; acc3[r] *= alpha;
        }
      }
      m_run = m_new;

#pragma unroll
      for (int r = 0; r < 16; ++r) st[r] = exp2_fast(st[r] - m_new);
      float s0 = (st[0] + st[1]) + (st[2] + st[3]), s1 = (st[4] + st[5]) + (st[6] + st[7]);
      float s2 = (st[8] + st[9]) + (st[10] + st[11]), s3 = (st[12] + st[13]) + (st[14] + st[15]);
      float lsum = (s0 + s1) + (s2 + s3);
      lsum += __shfl_xor(lsum, 32);
      l_run += lsum;

      short8 pB0, pB1;
#pragma unroll
      for (int c2 = 0; c2 < 2; ++c2) {
        const int o = c2 * 8;
        const uint32_t P01 = cvt_pk_bf16(st[o + 0], st[o + 1]);
        const uint32_t P23 = cvt_pk_bf16(st[o + 2], st[o + 3]);
        const uint32_t P45 = cvt_pk_bf16(st[o + 4], st[o + 5]);
        const uint32_t P67 = cvt_pk_bf16(st[o + 6], st[o + 7]);
        const uint32_t S01 = (uint32_t)__shfl_xor((int)P01, 32);
        const uint32_t S23 = (uint32_t)__shfl_xor((int)P23, 32);
        const uint32_t S45 = (uint32_t)__shfl_xor((int)P45, 32);
        const uint32_t S67 = (uint32_t)__shfl_xor((int)P67, 32);
        union { uint32_t ww[4]; short8 s8; } u;
        u.ww[0] = hi ? S45 : P01;
        u.ww[1] = hi ? S67 : P23;
        u.ww[2] = hi ? P45 : S01;
        u.ww[3] = hi ? P67 : S23;
        if (c2 == 0) pB0 = u.s8; else pB1 = u.s8;
      }

      __builtin_amdgcn_s_setprio(1);
      acc0 = __builtin_amdgcn_mfma_f32_32x32x16_bf16(vf[0], pB0, acc0, 0, 0, 0);
      acc1 = __builtin_amdgcn_mfma_f32_32x32x16_bf16(vf[1], pB0, acc1, 0, 0, 0);
      acc2 = __builtin_amdgcn_mfma_f32_32x32x16_bf16(vf[2], pB0, acc2, 0, 0, 0);
      acc3 = __builtin_amdgcn_mfma_f32_32x32x16_bf16(vf[3], pB0, acc3, 0, 0, 0);
      acc0 = __builtin_amdgcn_mfma_f32_32x32x16_bf16(vf[4], pB1, acc0, 0, 0, 0);
      acc1 = __builtin_amdgcn_mfma_f32_32x32x16_bf16(vf[5], pB1, acc1, 0, 0, 0);
      acc2 = __builtin_amdgcn_mfma_f32_32x32x16_bf16(vf[6], pB1, acc2, 0, 0, 0);
      acc3 = __builtin_amdgcn_mfma_f32_32x32x16_bf16(vf[7], pB1, acc3, 0, 0, 0);
      __builtin_amdgcn_s_setprio(0);
    }

    asm volatile("s_waitcnt lgkmcnt(0)" ::: "memory");
    __builtin_amdgcn_sched_barrier(0);
    __builtin_amdgcn_s_barrier();
    if (tt + 2 < Tblk) stage(tt + 2, cur);
  }

  const float inv = 1.f / l_run;
  const size_t orow = (size_t)(b * N + q0 + l31) * 2048 + h * 128;
#pragma unroll
  for (int r = 0; r < 16; r += 2) {
    const int doff = (r & 3) + 8 * ((r >> 2) & 1) + 16 * (r >> 3) + 4 * hi;
    *(uint32_t*)&Ao[orow + 0  + doff] = cvt_pk_bf16(acc0[r] * inv, acc0[r + 1] * inv);
    *(uint32_t*)&Ao[orow + 32 + doff] = cvt_pk_bf16(acc1[r] * inv, acc1[r + 1] * inv);
    *(uint32_t*)&Ao[orow + 64 + doff] = cvt_pk_bf16(acc2[r] * inv, acc2[r + 1] * inv);
    *(uint32_t*)&Ao[orow + 96 + doff] = cvt_pk_bf16(acc3[r] * inv, acc3[r + 1] * inv);
  }
}

extern "C" void kernel_launch(void* const* d_in, const int* in_sizes, int n_in,
                              void* d_out, int out_size, void* d_ws, size_t ws_size,
                              hipStream_t stream) {
  const float* x      = (const float*)d_in[0];
  const int*   pos    = (const int*)d_in[1];
  const float* Wqkv   = (const float*)d_in[2];
  const float* Wproj  = (const float*)d_in[3];
  float* out = (float*)d_out;

  const int N = 2048, C = 2048;
  const int M = 2 * N;

  char* ws = (char*)d_ws;
  unsigned short* Xb      = (unsigned short*)(ws + 0);            // 16 MiB, reused as Ao
  unsigned short* Wqkv_t  = (unsigned short*)(ws + 16777216);     // 24 MiB
  unsigned short* Wproj_t = (unsigned short*)(ws + 41943040);     // 8 MiB
  float*          cosT    = (float*)(ws + 50331648);              // 512 KiB (old Y space)
  float*          sinT    = (float*)(ws + 50855936);              // 512 KiB
  unsigned short* Qb      = (unsigned short*)(ws + 100663296);    // 16 MiB
  unsigned short* Kb      = (unsigned short*)(ws + 117440512);    // 16 MiB
  unsigned short* Vt      = (unsigned short*)(ws + 134217728);    // 16 MiB
  unsigned short* Ao = Xb;

  cast_bf16_kernel<<<(M * C) / 1024, 256, 0, stream>>>(x, Xb, M * C);
  transpose_cast_kernel<<<dim3(3 * C / 32, C / 32), 256, 0, stream>>>(Wqkv, Wqkv_t, C, 3 * C);
  transpose_cast_kernel<<<dim3(C / 32, C / 32), 256, 0, stream>>>(Wproj, Wproj_t, C, C);
  rope_table<<<512, 256, 0, stream>>>(cosT, sinT);
  gemm_qkv_rope<<<dim3(3 * C / 128, M / 256), 512, 0, stream>>>(
      Xb, Wqkv_t, pos, cosT, sinT, Qb, Kb, Vt, M, 3 * C, C);
  flash_attn4<<<dim3(32, 16), 256, 0, stream>>>(Qb, Kb, Vt, Ao, N);
  gemm_bt64<0><<<dim3(C / 128, M / 256), 512, 0, stream>>>(Ao, Wproj_t, out, M, C, C);
}

// Round 17
// 250.960 us; speedup vs baseline: 1.1950x; 1.0575x over previous
//
#include <hip/hip_runtime.h>
#include <stdint.h>

#define DEV __device__ __forceinline__

typedef __attribute__((ext_vector_type(8))) short short8;
typedef __attribute__((ext_vector_type(8))) unsigned short ushort8;
typedef __attribute__((ext_vector_type(4))) float f32x4;
typedef __attribute__((ext_vector_type(16))) float f32x16;
typedef __attribute__((ext_vector_type(2))) unsigned int uint2v;

DEV unsigned short f2bf(float f) {
  union { float f; uint32_t u; } v; v.f = f;
  uint32_t u = v.u;
  u += 0x7FFFu + ((u >> 16) & 1);  // RNE
  return (unsigned short)(u >> 16);
}
DEV float bf2f(unsigned short s) {
  union { uint32_t u; float f; } v; v.u = ((uint32_t)s) << 16;
  return v.f;
}
DEV float exp2_fast(float x) {
  float r; asm("v_exp_f32 %0, %1" : "=v"(r) : "v"(x)); return r;
}
DEV uint32_t cvt_pk_bf16(float lo, float hi) {
  uint32_t r; asm("v_cvt_pk_bf16_f32 %0, %1, %2" : "=v"(r) : "v"(lo), "v"(hi)); return r;
}

DEV void async_ld16(void* lds, const void* g) {
  __builtin_amdgcn_global_load_lds(
      (const __attribute__((address_space(1))) unsigned int*)g,
      (__attribute__((address_space(3))) unsigned int*)lds, 16, 0, 0);
}

#define QSCALE 0.12751743f

// ---------------- cast fp32 -> bf16 (vectorized) ----------------
__global__ __launch_bounds__(256) void cast_bf16_kernel(
    const float* __restrict__ in, unsigned short* __restrict__ out, int n) {
  int i = (blockIdx.x * 256 + threadIdx.x) * 4;
  if (i >= n) return;
  f32x4 v = *(const f32x4*)(in + i);
  union { unsigned short u[4]; uint2v v2; } o;
#pragma unroll
  for (int j = 0; j < 4; ++j) o.u[j] = f2bf(v[j]);
  *(uint2v*)(out + i) = o.v2;
}

// ------------- transpose + cast: in fp32 [R][C] -> out bf16 [C][R] -------------
__global__ __launch_bounds__(256) void transpose_cast_kernel(
    const float* __restrict__ in, unsigned short* __restrict__ out, int R, int C) {
  __shared__ float tile[32][33];
  const int c0 = blockIdx.x * 32, r0 = blockIdx.y * 32;
  const int tx = threadIdx.x & 31, ty = threadIdx.x >> 5;  // 32 x 8
#pragma unroll
  for (int i = 0; i < 32; i += 8)
    tile[ty + i][tx] = in[(size_t)(r0 + ty + i) * C + c0 + tx];
  __syncthreads();
#pragma unroll
  for (int i = 0; i < 32; i += 8)
    out[(size_t)(c0 + ty + i) * R + r0 + tx] = f2bf(tile[tx][ty + i]);
}

// ------------- rope tables: cosT/sinT [2048][64] fp32 -------------
__global__ __launch_bounds__(256) void rope_table(
    float* __restrict__ cosT, float* __restrict__ sinT) {
  const int i = blockIdx.x * 256 + threadIdx.x;  // 131072 total
  const int n = i >> 6, d = i & 63;
  const float ang = (float)n * exp2f((float)d * -0.2076205059304601f);
  cosT[i] = cosf(ang);
  sinT[i] = sinf(ang);
}

// ------------ gemm_bt64: EXACT r11 GEMM (proj: ~39 us) ------------
template <int OUT_BF16>
__global__ __launch_bounds__(512, 2) void gemm_bt64(
    const unsigned short* __restrict__ A, const unsigned short* __restrict__ Bt,
    void* __restrict__ Cout, int M, int Nn, int K) {
  __shared__ unsigned short As[2][256 * 64];  // 64 KiB
  __shared__ unsigned short Bs[2][128 * 64];  // 32 KiB
  const int t = threadIdx.x;
  const int lane = t & 63, w = t >> 6;
  const int wr = (w >> 1) * 64;
  const int wc = (w & 1) * 64;
  const int brow = blockIdx.y * 256, bcol = blockIdx.x * 128;
  const int l15 = lane & 15, lk = lane >> 4;
  const int p = l15 & 7;

  f32x4 acc[4][4] = {};

  auto stage = [&](int buf, int ktile) {
    const int koff = ktile * 64;
#pragma unroll
    for (int j = 0; j < 4; ++j) {
      const int slot = j * 512 + t;
      const int row = slot >> 3, ch = slot & 7;
      const int sc = ch ^ (row & 7);
      async_ld16(&As[buf][slot * 8], A + (size_t)(brow + row) * K + koff + sc * 8);
    }
#pragma unroll
    for (int j = 0; j < 2; ++j) {
      const int slot = j * 512 + t;
      const int row = slot >> 3, ch = slot & 7;
      const int sc = ch ^ (row & 7);
      async_ld16(&Bs[buf][slot * 8], Bt + (size_t)(bcol + row) * K + koff + sc * 8);
    }
  };

  const int NT = K / 64;
  stage(0, 0);
  stage(1, 1);

  for (int kt = 0; kt < NT; ++kt) {
    const int cur = kt & 1;
    if (kt == NT - 1) { asm volatile("s_waitcnt vmcnt(0)" ::: "memory"); }
    else              { asm volatile("s_waitcnt vmcnt(6)" ::: "memory"); }
    __builtin_amdgcn_sched_barrier(0);
    __builtin_amdgcn_s_barrier();

    short8 af0[4], af1[4], bf0[4], bf1[4];
#pragma unroll
    for (int m = 0; m < 4; ++m) {
      const int row = wr + m * 16 + l15;
      af0[m] = *(const short8*)&As[cur][row * 64 + (lk ^ p) * 8];
      af1[m] = *(const short8*)&As[cur][row * 64 + ((4 + lk) ^ p) * 8];
    }
#pragma unroll
    for (int n = 0; n < 4; ++n) {
      const int row = wc + n * 16 + l15;
      bf0[n] = *(const short8*)&Bs[cur][row * 64 + (lk ^ p) * 8];
      bf1[n] = *(const short8*)&Bs[cur][row * 64 + ((4 + lk) ^ p) * 8];
    }

    __builtin_amdgcn_s_setprio(1);
#pragma unroll
    for (int m = 0; m < 4; ++m)
#pragma unroll
      for (int n = 0; n < 4; ++n)
        acc[m][n] = __builtin_amdgcn_mfma_f32_16x16x32_bf16(af0[m], bf0[n], acc[m][n], 0, 0, 0);
    __builtin_amdgcn_s_setprio(0);

    asm volatile("s_waitcnt lgkmcnt(0)" ::: "memory");
    __builtin_amdgcn_sched_barrier(0);
    __builtin_amdgcn_s_barrier();
    if (kt + 2 < NT) stage(cur, kt + 2);

    __builtin_amdgcn_s_setprio(1);
#pragma unroll
    for (int m = 0; m < 4; ++m)
#pragma unroll
      for (int n = 0; n < 4; ++n)
        acc[m][n] = __builtin_amdgcn_mfma_f32_16x16x32_bf16(af1[m], bf1[n], acc[m][n], 0, 0, 0);
    __builtin_amdgcn_s_setprio(0);
  }

#pragma unroll
  for (int m = 0; m < 4; ++m)
#pragma unroll
    for (int n = 0; n < 4; ++n)
#pragma unroll
      for (int j = 0; j < 4; ++j) {
        const int row = brow + wr + m * 16 + lk * 4 + j;
        const int col = bcol + wc + n * 16 + l15;
        if (OUT_BF16)
          ((unsigned short*)Cout)[(size_t)row * Nn + col] = f2bf(acc[m][n][j]);
        else
          ((float*)Cout)[(size_t)row * Nn + col] = acc[m][n][j];
      }
}

// ------------ gemm_qkv_rope: r11 K-loop + fused RoPE/pack epilogue (r16, proven) ------------
__global__ __launch_bounds__(512, 2) void gemm_qkv_rope(
    const unsigned short* __restrict__ A, const unsigned short* __restrict__ Bt,
    const int* __restrict__ pos, const float* __restrict__ cosT,
    const float* __restrict__ sinT, unsigned short* __restrict__ Qb,
    unsigned short* __restrict__ Kb, unsigned short* __restrict__ Vt,
    int M, int Nn, int K) {
  __shared__ unsigned short smem[49152];  // 96 KiB: As[2][16384] | Bs[2][8192]
  unsigned short* As = smem;
  unsigned short* Bs = smem + 32768;
  const int t = threadIdx.x;
  const int lane = t & 63, w = t >> 6;
  const int wr = (w >> 1) * 64;
  const int wc = (w & 1) * 64;
  const int brow = blockIdx.y * 256, bcol = blockIdx.x * 128;
  const int l15 = lane & 15, lk = lane >> 4;
  const int p = l15 & 7;

  f32x4 acc[4][4] = {};

  auto stage = [&](int buf, int ktile) {
    const int koff = ktile * 64;
#pragma unroll
    for (int j = 0; j < 4; ++j) {
      const int slot = j * 512 + t;
      const int row = slot >> 3, ch = slot & 7;
      const int sc = ch ^ (row & 7);
      async_ld16(&As[buf * 16384 + slot * 8], A + (size_t)(brow + row) * K + koff + sc * 8);
    }
#pragma unroll
    for (int j = 0; j < 2; ++j) {
      const int slot = j * 512 + t;
      const int row = slot >> 3, ch = slot & 7;
      const int sc = ch ^ (row & 7);
      async_ld16(&Bs[buf * 8192 + slot * 8], Bt + (size_t)(bcol + row) * K + koff + sc * 8);
    }
  };

  const int NT = K / 64;
  stage(0, 0);
  stage(1, 1);

  for (int kt = 0; kt < NT; ++kt) {
    const int cur = kt & 1;
    if (kt == NT - 1) { asm volatile("s_waitcnt vmcnt(0)" ::: "memory"); }
    else              { asm volatile("s_waitcnt vmcnt(6)" ::: "memory"); }
    __builtin_amdgcn_sched_barrier(0);
    __builtin_amdgcn_s_barrier();

    short8 af0[4], af1[4], bf0[4], bf1[4];
#pragma unroll
    for (int m = 0; m < 4; ++m) {
      const int row = wr + m * 16 + l15;
      af0[m] = *(const short8*)&As[cur * 16384 + row * 64 + (lk ^ p) * 8];
      af1[m] = *(const short8*)&As[cur * 16384 + row * 64 + ((4 + lk) ^ p) * 8];
    }
#pragma unroll
    for (int n = 0; n < 4; ++n) {
      const int row = wc + n * 16 + l15;
      bf0[n] = *(const short8*)&Bs[cur * 8192 + row * 64 + (lk ^ p) * 8];
      bf1[n] = *(const short8*)&Bs[cur * 8192 + row * 64 + ((4 + lk) ^ p) * 8];
    }

    __builtin_amdgcn_s_setprio(1);
#pragma unroll
    for (int m = 0; m < 4; ++m)
#pragma unroll
      for (int n = 0; n < 4; ++n)
        acc[m][n] = __builtin_amdgcn_mfma_f32_16x16x32_bf16(af0[m], bf0[n], acc[m][n], 0, 0, 0);
    __builtin_amdgcn_s_setprio(0);

    asm volatile("s_waitcnt lgkmcnt(0)" ::: "memory");
    __builtin_amdgcn_sched_barrier(0);
    __builtin_amdgcn_s_barrier();
    if (kt + 2 < NT) stage(cur, kt + 2);

    __builtin_amdgcn_s_setprio(1);
#pragma unroll
    for (int m = 0; m < 4; ++m)
#pragma unroll
      for (int n = 0; n < 4; ++n)
        acc[m][n] = __builtin_amdgcn_mfma_f32_16x16x32_bf16(af1[m], bf1[n], acc[m][n], 0, 0, 0);
    __builtin_amdgcn_s_setprio(0);
  }

  __syncthreads();  // all waves done with As/Bs -> smem reusable

  const int mode = bcol >> 11;        // 0=Q, 1=K, 2=V
  const int h = (bcol >> 7) & 15;
  const int b = brow >> 11, n0 = brow & 2047;

  if (mode == 2) {
#pragma unroll
    for (int m = 0; m < 4; ++m)
#pragma unroll
      for (int n = 0; n < 4; ++n) {
        const int d = wc + n * 16 + l15;
        const int tok = wr + m * 16 + lk * 4;
        union { unsigned short u[4]; uint2v v2; } pk;
#pragma unroll
        for (int j = 0; j < 4; ++j) pk.u[j] = f2bf(acc[m][n][j]);
        *(uint2v*)&smem[d * 264 + tok] = pk.v2;
      }
    __syncthreads();
    const size_t vbase = (size_t)(b * 16 + h) * 128 * 2048;
    const int half = t >> 5, l32 = t & 31;
#pragma unroll
    for (int pp = 0; pp < 8; ++pp) {
      const int d = pp * 16 + half;
      const int nl = l32 * 8;
      ushort8 v = *(const ushort8*)&smem[d * 264 + nl];
      *(ushort8*)&Vt[vbase + (size_t)d * 2048 + n0 + nl] = v;
    }
  } else {
    const float sc = (mode == 0) ? QSCALE : 1.0f;
#pragma unroll
    for (int m = 0; m < 4; ++m)
#pragma unroll
      for (int n = 0; n < 4; ++n) {
        const int d = wc + n * 16 + l15;
#pragma unroll
        for (int j = 0; j < 4; ++j) {
          const int r = wr + m * 16 + lk * 4 + j;
          smem[r * 136 + d] = f2bf(acc[m][n][j] * sc);
        }
      }
    __syncthreads();
    unsigned short* dst = (mode == 0) ? Qb : Kb;
    const int d0 = (t & 7) * 8;
#pragma unroll
    for (int pass = 0; pass < 4; ++pass) {
      const int r = pass * 64 + (t >> 3);
      const int prow = brow + r;
      const int pi = pos[prow];
      const short8 lo8 = *(const short8*)&smem[r * 136 + d0];
      const short8 hi8 = *(const short8*)&smem[r * 136 + 64 + d0];
      const f32x4 c0 = *(const f32x4*)&cosT[pi * 64 + d0];
      const f32x4 c1 = *(const f32x4*)&cosT[pi * 64 + d0 + 4];
      const f32x4 s0 = *(const f32x4*)&sinT[pi * 64 + d0];
      const f32x4 s1 = *(const f32x4*)&sinT[pi * 64 + d0 + 4];
      float olo[8], ohi[8];
#pragma unroll
      for (int i = 0; i < 8; ++i) {
        const float lo = bf2f((unsigned short)lo8[i]);
        const float hi = bf2f((unsigned short)hi8[i]);
        const float c = (i < 4) ? c0[i & 3] : c1[i & 3];
        const float s = (i < 4) ? s0[i & 3] : s1[i & 3];
        olo[i] = lo * c - hi * s;
        ohi[i] = hi * c + lo * s;
      }
      union { uint32_t w4[4]; ushort8 s8; } ulo, uhi;
#pragma unroll
      for (int k = 0; k < 4; ++k) {
        ulo.w4[k] = cvt_pk_bf16(olo[2 * k], olo[2 * k + 1]);
        uhi.w4[k] = cvt_pk_bf16(ohi[2 * k], ohi[2 * k + 1]);
      }
      const size_t base = ((size_t)((prow >> 11) * 16 + h) * 2048 + (prow & 2047)) * 128;
      *(ushort8*)&dst[base + d0] = ulo.s8;
      *(ushort8*)&dst[base + 64 + d0] = uhi.s8;
    }
  }
}

// ------------- causal flash attention: 4 waves/block, CU-paired chunks, KVBLK=64 -------------
// r17 single change vs r13: staged kv tile 32 -> 64 (two 32-kv subtiles per stage).
// Halves barrier-pairs + staging batches per sweep (per-CU 68 -> 34 steps); subtile 2's
// LDS reads/softmax overlap subtile 1's PV (no barrier between subtiles). LDS 64 KB,
// still 2 blocks/CU. Per-subtile math byte-identical; numerics unchanged.
__global__ __launch_bounds__(256, 2) void flash_attn4(
    const unsigned short* __restrict__ Qb, const unsigned short* __restrict__ Kb,
    const unsigned short* __restrict__ Vt, unsigned short* __restrict__ Ao, int N) {
  __shared__ unsigned short Ks[2][64 * 128];   // [kv][d], 16 KiB each
  __shared__ unsigned short Vs[2][128 * 64];   // [d][kv], 16 KiB each
  const int t = threadIdx.x, lane = t & 63, w = t >> 6;          // 4 waves
  const int bh = blockIdx.x, b = bh >> 4, h = bh & 15;
  const int y = blockIdx.y;
  const int cc = (y < 8) ? (15 - y) : (y - 8);   // heavy chunks first; y,y+8 sum to 15
  const int q0 = cc * 128 + w * 32;
  const int l31 = lane & 31, hi = lane >> 5;
  const size_t base = (size_t)bh * N * 128;
  const size_t vbase = (size_t)bh * 128 * N;
  const int Tblk = 2 * cc + 2;      // 64-wide tiles in the block sweep

  auto stage = [&](int tt, int buf) {
    const int kv0 = tt * 64;
#pragma unroll
    for (int j = 0; j < 4; ++j) {   // K: 64x128 shorts = 1024 chunks, 4/thread
      const int slot = j * 256 + t;
      const int krow = slot >> 4, kch = (slot & 15) ^ (krow & 7);
      async_ld16(&Ks[buf][slot * 8], Kb + base + (size_t)(kv0 + krow) * 128 + kch * 8);
    }
#pragma unroll
    for (int j = 0; j < 4; ++j) {   // V: 128x64 shorts = 1024 chunks, 4/thread
      const int slot = j * 256 + t;
      const int vrow = slot >> 3, vch = (slot & 7) ^ (vrow & 7);
      async_ld16(&Vs[buf][slot * 8], Vt + vbase + (size_t)vrow * N + kv0 + vch * 8);
    }
  };

  short8 qf[8];
#pragma unroll
  for (int s = 0; s < 8; ++s)
    qf[s] = *(const short8*)&Qb[base + (size_t)(q0 + l31) * 128 + s * 16 + hi * 8];

  f32x16 acc0 = {}, acc1 = {}, acc2 = {}, acc3 = {};
  float m_run = -1e30f, l_run = 0.f;

  stage(0, 0);
  stage(1, 1);

  for (int tt = 0; tt < Tblk; ++tt) {
    const int cur = tt & 1;
    if (tt < Tblk - 1) { asm volatile("s_waitcnt vmcnt(8)" ::: "memory"); }
    else               { asm volatile("s_waitcnt vmcnt(0)" ::: "memory"); }
    __builtin_amdgcn_sched_barrier(0);
    __builtin_amdgcn_s_barrier();

#pragma unroll
    for (int sb = 0; sb < 2; ++sb) {
      const int kv0 = tt * 64 + sb * 32;
      if (kv0 <= q0) {
        const bool masked = (kv0 == q0);

        short8 kf[8];
#pragma unroll
        for (int s = 0; s < 8; ++s)
          kf[s] = *(const short8*)&Ks[cur][(sb * 32 + l31) * 128 + ((2 * s + hi) ^ (l31 & 7)) * 8];
        short8 vf[8];
#pragma unroll
        for (int c2 = 0; c2 < 2; ++c2)
#pragma unroll
          for (int dblk = 0; dblk < 4; ++dblk) {
            const int row = dblk * 32 + l31;
            vf[c2 * 4 + dblk] =
                *(const short8*)&Vs[cur][row * 64 + ((sb * 4 + 2 * c2 + hi) ^ (row & 7)) * 8];
          }

        f32x16 st = {};
        __builtin_amdgcn_s_setprio(1);
#pragma unroll
        for (int s = 0; s < 8; ++s)
          st = __builtin_amdgcn_mfma_f32_32x32x16_bf16(kf[s], qf[s], st, 0, 0, 0);
        __builtin_amdgcn_s_setprio(0);

        if (masked) {
          const int qg = q0 + l31;
#pragma unroll
          for (int r = 0; r < 16; ++r) {
            const int kvg = kv0 + (r & 3) + 8 * ((r >> 2) & 1) + 16 * (r >> 3) + 4 * hi;
            st[r] = (kvg > qg) ? -1e30f : st[r];
          }
        }
        float a0 = fmaxf(st[0], st[1]),  a1 = fmaxf(st[2], st[3]),
              a2 = fmaxf(st[4], st[5]),  a3 = fmaxf(st[6], st[7]),
              a4 = fmaxf(st[8], st[9]),  a5 = fmaxf(st[10], st[11]),
              a6 = fmaxf(st[12], st[13]), a7 = fmaxf(st[14], st[15]);
        a0 = fmaxf(a0, a1); a2 = fmaxf(a2, a3); a4 = fmaxf(a4, a5); a6 = fmaxf(a6, a7);
        a0 = fmaxf(a0, a2); a4 = fmaxf(a4, a6);
        float mt = fmaxf(a0, a4);
        mt = fmaxf(mt, __shfl_xor(mt, 32));

        float m_new = fmaxf(m_run, mt);
        const bool defer = __all(mt - m_run <= 8.f);  // T13
        if (defer) {
          m_new = m_run;
        } else {
          const float alpha = exp2_fast(m_run - m_new);
          l_run *= alpha;
#pragma unroll
          for (int r = 0; r < 16; ++r) {
            acc0[r] *= alpha; acc1[r] *= alpha; acc2[r] *= alpha; acc3[r] *= alpha;
          }
        }
        m_run = m_new;

#pragma unroll
        for (int r = 0; r < 16; ++r) st[r] = exp2_fast(st[r] - m_new);
        float s0 = (st[0] + st[1]) + (st[2] + st[3]), s1 = (st[4] + st[5]) + (st[6] + st[7]);
        float s2 = (st[8] + st[9]) + (st[10] + st[11]), s3 = (st[12] + st[13]) + (st[14] + st[15]);
        float lsum = (s0 + s1) + (s2 + s3);
        lsum += __shfl_xor(lsum, 32);
        l_run += lsum;

        short8 pB0, pB1;
#pragma unroll
        for (int c2 = 0; c2 < 2; ++c2) {
          const int o = c2 * 8;
          const uint32_t P01 = cvt_pk_bf16(st[o + 0], st[o + 1]);
          const uint32_t P23 = cvt_pk_bf16(st[o + 2], st[o + 3]);
          const uint32_t P45 = cvt_pk_bf16(st[o + 4], st[o + 5]);
          const uint32_t P67 = cvt_pk_bf16(st[o + 6], st[o + 7]);
          const uint32_t S01 = (uint32_t)__shfl_xor((int)P01, 32);
          const uint32_t S23 = (uint32_t)__shfl_xor((int)P23, 32);
          const uint32_t S45 = (uint32_t)__shfl_xor((int)P45, 32);
          const uint32_t S67 = (uint32_t)__shfl_xor((int)P67, 32);
          union { uint32_t ww[4]; short8 s8; } u;
          u.ww[0] = hi ? S45 : P01;
          u.ww[1] = hi ? S67 : P23;
          u.ww[2] = hi ? P45 : S01;
          u.ww[3] = hi ? P67 : S23;
          if (c2 == 0) pB0 = u.s8; else pB1 = u.s8;
        }

        __builtin_amdgcn_s_setprio(1);
        acc0 = __builtin_amdgcn_mfma_f32_32x32x16_bf16(vf[0], pB0, acc0, 0, 0, 0);
        acc1 = __builtin_amdgcn_mfma_f32_32x32x16_bf16(vf[1], pB0, acc1, 0, 0, 0);
        acc2 = __builtin_amdgcn_mfma_f32_32x32x16_bf16(vf[2], pB0, acc2, 0, 0, 0);
        acc3 = __builtin_amdgcn_mfma_f32_32x32x16_bf16(vf[3], pB0, acc3, 0, 0, 0);
        acc0 = __builtin_amdgcn_mfma_f32_32x32x16_bf16(vf[4], pB1, acc0, 0, 0, 0);
        acc1 = __builtin_amdgcn_mfma_f32_32x32x16_bf16(vf[5], pB1, acc1, 0, 0, 0);
        acc2 = __builtin_amdgcn_mfma_f32_32x32x16_bf16(vf[6], pB1, acc2, 0, 0, 0);
        acc3 = __builtin_amdgcn_mfma_f32_32x32x16_bf16(vf[7], pB1, acc3, 0, 0, 0);
        __builtin_amdgcn_s_setprio(0);
      }
    }

    asm volatile("s_waitcnt lgkmcnt(0)" ::: "memory");
    __builtin_amdgcn_sched_barrier(0);
    __builtin_amdgcn_s_barrier();
    if (tt + 2 < Tblk) stage(tt + 2, cur);
  }

  const float inv = 1.f / l_run;
  const size_t orow = (size_t)(b * N + q0 + l31) * 2048 + h * 128;
#pragma unroll
  for (int r = 0; r < 16; r += 2) {
    const int doff = (r & 3) + 8 * ((r >> 2) & 1) + 16 * (r >> 3) + 4 * hi;
    *(uint32_t*)&Ao[orow + 0  + doff] = cvt_pk_bf16(acc0[r] * inv, acc0[r + 1] * inv);
    *(uint32_t*)&Ao[orow + 32 + doff] = cvt_pk_bf16(acc1[r] * inv, acc1[r + 1] * inv);
    *(uint32_t*)&Ao[orow + 64 + doff] = cvt_pk_bf16(acc2[r] * inv, acc2[r + 1] * inv);
    *(uint32_t*)&Ao[orow + 96 + doff] = cvt_pk_bf16(acc3[r] * inv, acc3[r + 1] * inv);
  }
}

extern "C" void kernel_launch(void* const* d_in, const int* in_sizes, int n_in,
                              void* d_out, int out_size, void* d_ws, size_t ws_size,
                              hipStream_t stream) {
  const float* x      = (const float*)d_in[0];
  const int*   pos    = (const int*)d_in[1];
  const float* Wqkv   = (const float*)d_in[2];
  const float* Wproj  = (const float*)d_in[3];
  float* out = (float*)d_out;

  const int N = 2048, C = 2048;
  const int M = 2 * N;

  char* ws = (char*)d_ws;
  unsigned short* Xb      = (unsigned short*)(ws + 0);            // 16 MiB, reused as Ao
  unsigned short* Wqkv_t  = (unsigned short*)(ws + 16777216);     // 24 MiB
  unsigned short* Wproj_t = (unsigned short*)(ws + 41943040);     // 8 MiB
  float*          cosT    = (float*)(ws + 50331648);              // 512 KiB
  float*          sinT    = (float*)(ws + 50855936);              // 512 KiB
  unsigned short* Qb      = (unsigned short*)(ws + 100663296);    // 16 MiB
  unsigned short* Kb      = (unsigned short*)(ws + 117440512);    // 16 MiB
  unsigned short* Vt      = (unsigned short*)(ws + 134217728);    // 16 MiB
  unsigned short* Ao = Xb;

  cast_bf16_kernel<<<(M * C) / 1024, 256, 0, stream>>>(x, Xb, M * C);
  transpose_cast_kernel<<<dim3(3 * C / 32, C / 32), 256, 0, stream>>>(Wqkv, Wqkv_t, C, 3 * C);
  transpose_cast_kernel<<<dim3(C / 32, C / 32), 256, 0, stream>>>(Wproj, Wproj_t, C, C);
  rope_table<<<512, 256, 0, stream>>>(cosT, sinT);
  gemm_qkv_rope<<<dim3(3 * C / 128, M / 256), 512, 0, stream>>>(
      Xb, Wqkv_t, pos, cosT, sinT, Qb, Kb, Vt, M, 3 * C, C);
  flash_attn4<<<dim3(32, 16), 256, 0, stream>>>(Qb, Kb, Vt, Ao, N);
  gemm_bt64<0><<<dim3(C / 128, M / 256), 512, 0, stream>>>(Ao, Wproj_t, out, M, C, C);
}

// Round 18
// 250.115 us; speedup vs baseline: 1.1990x; 1.0034x over previous
//
#include <hip/hip_runtime.h>
#include <stdint.h>

#define DEV __device__ __forceinline__

typedef __attribute__((ext_vector_type(8))) short short8;
typedef __attribute__((ext_vector_type(8))) unsigned short ushort8;
typedef __attribute__((ext_vector_type(4))) float f32x4;
typedef __attribute__((ext_vector_type(16))) float f32x16;
typedef __attribute__((ext_vector_type(2))) unsigned int uint2v;

DEV unsigned short f2bf(float f) {
  union { float f; uint32_t u; } v; v.f = f;
  uint32_t u = v.u;
  u += 0x7FFFu + ((u >> 16) & 1);  // RNE
  return (unsigned short)(u >> 16);
}
DEV float bf2f(unsigned short s) {
  union { uint32_t u; float f; } v; v.u = ((uint32_t)s) << 16;
  return v.f;
}
DEV float exp2_fast(float x) {
  float r; asm("v_exp_f32 %0, %1" : "=v"(r) : "v"(x)); return r;
}
DEV uint32_t cvt_pk_bf16(float lo, float hi) {
  uint32_t r; asm("v_cvt_pk_bf16_f32 %0, %1, %2" : "=v"(r) : "v"(lo), "v"(hi)); return r;
}

DEV void async_ld16(void* lds, const void* g) {
  __builtin_amdgcn_global_load_lds(
      (const __attribute__((address_space(1))) unsigned int*)g,
      (__attribute__((address_space(3))) unsigned int*)lds, 16, 0, 0);
}

#define QSCALE 0.12751743f

// ---------------- cast fp32 -> bf16 (vectorized) ----------------
__global__ __launch_bounds__(256) void cast_bf16_kernel(
    const float* __restrict__ in, unsigned short* __restrict__ out, int n) {
  int i = (blockIdx.x * 256 + threadIdx.x) * 4;
  if (i >= n) return;
  f32x4 v = *(const f32x4*)(in + i);
  union { unsigned short u[4]; uint2v v2; } o;
#pragma unroll
  for (int j = 0; j < 4; ++j) o.u[j] = f2bf(v[j]);
  *(uint2v*)(out + i) = o.v2;
}

// ------------- transpose + cast: in fp32 [R][C] -> out bf16 [C][R] -------------
__global__ __launch_bounds__(256) void transpose_cast_kernel(
    const float* __restrict__ in, unsigned short* __restrict__ out, int R, int C) {
  __shared__ float tile[32][33];
  const int c0 = blockIdx.x * 32, r0 = blockIdx.y * 32;
  const int tx = threadIdx.x & 31, ty = threadIdx.x >> 5;  // 32 x 8
#pragma unroll
  for (int i = 0; i < 32; i += 8)
    tile[ty + i][tx] = in[(size_t)(r0 + ty + i) * C + c0 + tx];
  __syncthreads();
#pragma unroll
  for (int i = 0; i < 32; i += 8)
    out[(size_t)(c0 + ty + i) * R + r0 + tx] = f2bf(tile[tx][ty + i]);
}

// ------------- rope tables: cosT/sinT [2048][64] fp32 -------------
__global__ __launch_bounds__(256) void rope_table(
    float* __restrict__ cosT, float* __restrict__ sinT) {
  const int i = blockIdx.x * 256 + threadIdx.x;  // 131072 total
  const int n = i >> 6, d = i & 63;
  const float ang = (float)n * exp2f((float)d * -0.2076205059304601f);
  cosT[i] = cosf(ang);
  sinT[i] = sinf(ang);
}

// ------------ gemm_bt64: EXACT r11 GEMM (proj: ~39 us) ------------
template <int OUT_BF16>
__global__ __launch_bounds__(512, 2) void gemm_bt64(
    const unsigned short* __restrict__ A, const unsigned short* __restrict__ Bt,
    void* __restrict__ Cout, int M, int Nn, int K) {
  __shared__ unsigned short As[2][256 * 64];  // 64 KiB
  __shared__ unsigned short Bs[2][128 * 64];  // 32 KiB
  const int t = threadIdx.x;
  const int lane = t & 63, w = t >> 6;
  const int wr = (w >> 1) * 64;
  const int wc = (w & 1) * 64;
  const int brow = blockIdx.y * 256, bcol = blockIdx.x * 128;
  const int l15 = lane & 15, lk = lane >> 4;
  const int p = l15 & 7;

  f32x4 acc[4][4] = {};

  auto stage = [&](int buf, int ktile) {
    const int koff = ktile * 64;
#pragma unroll
    for (int j = 0; j < 4; ++j) {
      const int slot = j * 512 + t;
      const int row = slot >> 3, ch = slot & 7;
      const int sc = ch ^ (row & 7);
      async_ld16(&As[buf][slot * 8], A + (size_t)(brow + row) * K + koff + sc * 8);
    }
#pragma unroll
    for (int j = 0; j < 2; ++j) {
      const int slot = j * 512 + t;
      const int row = slot >> 3, ch = slot & 7;
      const int sc = ch ^ (row & 7);
      async_ld16(&Bs[buf][slot * 8], Bt + (size_t)(bcol + row) * K + koff + sc * 8);
    }
  };

  const int NT = K / 64;
  stage(0, 0);
  stage(1, 1);

  for (int kt = 0; kt < NT; ++kt) {
    const int cur = kt & 1;
    if (kt == NT - 1) { asm volatile("s_waitcnt vmcnt(0)" ::: "memory"); }
    else              { asm volatile("s_waitcnt vmcnt(6)" ::: "memory"); }
    __builtin_amdgcn_sched_barrier(0);
    __builtin_amdgcn_s_barrier();

    short8 af0[4], af1[4], bf0[4], bf1[4];
#pragma unroll
    for (int m = 0; m < 4; ++m) {
      const int row = wr + m * 16 + l15;
      af0[m] = *(const short8*)&As[cur][row * 64 + (lk ^ p) * 8];
      af1[m] = *(const short8*)&As[cur][row * 64 + ((4 + lk) ^ p) * 8];
    }
#pragma unroll
    for (int n = 0; n < 4; ++n) {
      const int row = wc + n * 16 + l15;
      bf0[n] = *(const short8*)&Bs[cur][row * 64 + (lk ^ p) * 8];
      bf1[n] = *(const short8*)&Bs[cur][row * 64 + ((4 + lk) ^ p) * 8];
    }

    __builtin_amdgcn_s_setprio(1);
#pragma unroll
    for (int m = 0; m < 4; ++m)
#pragma unroll
      for (int n = 0; n < 4; ++n)
        acc[m][n] = __builtin_amdgcn_mfma_f32_16x16x32_bf16(af0[m], bf0[n], acc[m][n], 0, 0, 0);
    __builtin_amdgcn_s_setprio(0);

    asm volatile("s_waitcnt lgkmcnt(0)" ::: "memory");
    __builtin_amdgcn_sched_barrier(0);
    __builtin_amdgcn_s_barrier();
    if (kt + 2 < NT) stage(cur, kt + 2);

    __builtin_amdgcn_s_setprio(1);
#pragma unroll
    for (int m = 0; m < 4; ++m)
#pragma unroll
      for (int n = 0; n < 4; ++n)
        acc[m][n] = __builtin_amdgcn_mfma_f32_16x16x32_bf16(af1[m], bf1[n], acc[m][n], 0, 0, 0);
    __builtin_amdgcn_s_setprio(0);
  }

#pragma unroll
  for (int m = 0; m < 4; ++m)
#pragma unroll
    for (int n = 0; n < 4; ++n)
#pragma unroll
      for (int j = 0; j < 4; ++j) {
        const int row = brow + wr + m * 16 + lk * 4 + j;
        const int col = bcol + wc + n * 16 + l15;
        if (OUT_BF16)
          ((unsigned short*)Cout)[(size_t)row * Nn + col] = f2bf(acc[m][n][j]);
        else
          ((float*)Cout)[(size_t)row * Nn + col] = acc[m][n][j];
      }
}

// ------------ gemm_qkv_rope: r11 K-loop + fused RoPE/pack epilogue (r16, proven) ------------
__global__ __launch_bounds__(512, 2) void gemm_qkv_rope(
    const unsigned short* __restrict__ A, const unsigned short* __restrict__ Bt,
    const int* __restrict__ pos, const float* __restrict__ cosT,
    const float* __restrict__ sinT, unsigned short* __restrict__ Qb,
    unsigned short* __restrict__ Kb, unsigned short* __restrict__ Vt,
    int M, int Nn, int K) {
  __shared__ unsigned short smem[49152];  // 96 KiB: As[2][16384] | Bs[2][8192]
  unsigned short* As = smem;
  unsigned short* Bs = smem + 32768;
  const int t = threadIdx.x;
  const int lane = t & 63, w = t >> 6;
  const int wr = (w >> 1) * 64;
  const int wc = (w & 1) * 64;
  const int brow = blockIdx.y * 256, bcol = blockIdx.x * 128;
  const int l15 = lane & 15, lk = lane >> 4;
  const int p = l15 & 7;

  f32x4 acc[4][4] = {};

  auto stage = [&](int buf, int ktile) {
    const int koff = ktile * 64;
#pragma unroll
    for (int j = 0; j < 4; ++j) {
      const int slot = j * 512 + t;
      const int row = slot >> 3, ch = slot & 7;
      const int sc = ch ^ (row & 7);
      async_ld16(&As[buf * 16384 + slot * 8], A + (size_t)(brow + row) * K + koff + sc * 8);
    }
#pragma unroll
    for (int j = 0; j < 2; ++j) {
      const int slot = j * 512 + t;
      const int row = slot >> 3, ch = slot & 7;
      const int sc = ch ^ (row & 7);
      async_ld16(&Bs[buf * 8192 + slot * 8], Bt + (size_t)(bcol + row) * K + koff + sc * 8);
    }
  };

  const int NT = K / 64;
  stage(0, 0);
  stage(1, 1);

  for (int kt = 0; kt < NT; ++kt) {
    const int cur = kt & 1;
    if (kt == NT - 1) { asm volatile("s_waitcnt vmcnt(0)" ::: "memory"); }
    else              { asm volatile("s_waitcnt vmcnt(6)" ::: "memory"); }
    __builtin_amdgcn_sched_barrier(0);
    __builtin_amdgcn_s_barrier();

    short8 af0[4], af1[4], bf0[4], bf1[4];
#pragma unroll
    for (int m = 0; m < 4; ++m) {
      const int row = wr + m * 16 + l15;
      af0[m] = *(const short8*)&As[cur * 16384 + row * 64 + (lk ^ p) * 8];
      af1[m] = *(const short8*)&As[cur * 16384 + row * 64 + ((4 + lk) ^ p) * 8];
    }
#pragma unroll
    for (int n = 0; n < 4; ++n) {
      const int row = wc + n * 16 + l15;
      bf0[n] = *(const short8*)&Bs[cur * 8192 + row * 64 + (lk ^ p) * 8];
      bf1[n] = *(const short8*)&Bs[cur * 8192 + row * 64 + ((4 + lk) ^ p) * 8];
    }

    __builtin_amdgcn_s_setprio(1);
#pragma unroll
    for (int m = 0; m < 4; ++m)
#pragma unroll
      for (int n = 0; n < 4; ++n)
        acc[m][n] = __builtin_amdgcn_mfma_f32_16x16x32_bf16(af0[m], bf0[n], acc[m][n], 0, 0, 0);
    __builtin_amdgcn_s_setprio(0);

    asm volatile("s_waitcnt lgkmcnt(0)" ::: "memory");
    __builtin_amdgcn_sched_barrier(0);
    __builtin_amdgcn_s_barrier();
    if (kt + 2 < NT) stage(cur, kt + 2);

    __builtin_amdgcn_s_setprio(1);
#pragma unroll
    for (int m = 0; m < 4; ++m)
#pragma unroll
      for (int n = 0; n < 4; ++n)
        acc[m][n] = __builtin_amdgcn_mfma_f32_16x16x32_bf16(af1[m], bf1[n], acc[m][n], 0, 0, 0);
    __builtin_amdgcn_s_setprio(0);
  }

  __syncthreads();  // all waves done with As/Bs -> smem reusable

  const int mode = bcol >> 11;        // 0=Q, 1=K, 2=V
  const int h = (bcol >> 7) & 15;
  const int b = brow >> 11, n0 = brow & 2047;

  if (mode == 2) {
#pragma unroll
    for (int m = 0; m < 4; ++m)
#pragma unroll
      for (int n = 0; n < 4; ++n) {
        const int d = wc + n * 16 + l15;
        const int tok = wr + m * 16 + lk * 4;
        union { unsigned short u[4]; uint2v v2; } pk;
#pragma unroll
        for (int j = 0; j < 4; ++j) pk.u[j] = f2bf(acc[m][n][j]);
        *(uint2v*)&smem[d * 264 + tok] = pk.v2;
      }
    __syncthreads();
    const size_t vbase = (size_t)(b * 16 + h) * 128 * 2048;
    const int half = t >> 5, l32 = t & 31;
#pragma unroll
    for (int pp = 0; pp < 8; ++pp) {
      const int d = pp * 16 + half;
      const int nl = l32 * 8;
      ushort8 v = *(const ushort8*)&smem[d * 264 + nl];
      *(ushort8*)&Vt[vbase + (size_t)d * 2048 + n0 + nl] = v;
    }
  } else {
    const float sc = (mode == 0) ? QSCALE : 1.0f;
#pragma unroll
    for (int m = 0; m < 4; ++m)
#pragma unroll
      for (int n = 0; n < 4; ++n) {
        const int d = wc + n * 16 + l15;
#pragma unroll
        for (int j = 0; j < 4; ++j) {
          const int r = wr + m * 16 + lk * 4 + j;
          smem[r * 136 + d] = f2bf(acc[m][n][j] * sc);
        }
      }
    __syncthreads();
    unsigned short* dst = (mode == 0) ? Qb : Kb;
    const int d0 = (t & 7) * 8;
#pragma unroll
    for (int pass = 0; pass < 4; ++pass) {
      const int r = pass * 64 + (t >> 3);
      const int prow = brow + r;
      const int pi = pos[prow];
      const short8 lo8 = *(const short8*)&smem[r * 136 + d0];
      const short8 hi8 = *(const short8*)&smem[r * 136 + 64 + d0];
      const f32x4 c0 = *(const f32x4*)&cosT[pi * 64 + d0];
      const f32x4 c1 = *(const f32x4*)&cosT[pi * 64 + d0 + 4];
      const f32x4 s0 = *(const f32x4*)&sinT[pi * 64 + d0];
      const f32x4 s1 = *(const f32x4*)&sinT[pi * 64 + d0 + 4];
      float olo[8], ohi[8];
#pragma unroll
      for (int i = 0; i < 8; ++i) {
        const float lo = bf2f((unsigned short)lo8[i]);
        const float hi = bf2f((unsigned short)hi8[i]);
        const float c = (i < 4) ? c0[i & 3] : c1[i & 3];
        const float s = (i < 4) ? s0[i & 3] : s1[i & 3];
        olo[i] = lo * c - hi * s;
        ohi[i] = hi * c + lo * s;
      }
      union { uint32_t w4[4]; ushort8 s8; } ulo, uhi;
#pragma unroll
      for (int k = 0; k < 4; ++k) {
        ulo.w4[k] = cvt_pk_bf16(olo[2 * k], olo[2 * k + 1]);
        uhi.w4[k] = cvt_pk_bf16(ohi[2 * k], ohi[2 * k + 1]);
      }
      const size_t base = ((size_t)((prow >> 11) * 16 + h) * 2048 + (prow & 2047)) * 128;
      *(ushort8*)&dst[base + d0] = ulo.s8;
      *(ushort8*)&dst[base + 64 + d0] = uhi.s8;
    }
  }
}

// ------------- causal flash attention: 4 waves/block, CU-paired chunks, KVBLK=64 -------------
// r18 single change vs r17: QK^T accumulator split into two independent 4-deep MFMA
// chains (stA: K-slices 0-3, stB: 4-7) summed after — halves the serial MFMA latency
// on the critical path before softmax. Max tree rewritten as nested fmaxf triples
// (clang fuses to v_max3_f32). Everything else byte-identical to r17.
__global__ __launch_bounds__(256, 2) void flash_attn4(
    const unsigned short* __restrict__ Qb, const unsigned short* __restrict__ Kb,
    const unsigned short* __restrict__ Vt, unsigned short* __restrict__ Ao, int N) {
  __shared__ unsigned short Ks[2][64 * 128];   // [kv][d], 16 KiB each
  __shared__ unsigned short Vs[2][128 * 64];   // [d][kv], 16 KiB each
  const int t = threadIdx.x, lane = t & 63, w = t >> 6;          // 4 waves
  const int bh = blockIdx.x, b = bh >> 4, h = bh & 15;
  const int y = blockIdx.y;
  const int cc = (y < 8) ? (15 - y) : (y - 8);   // heavy chunks first; y,y+8 sum to 15
  const int q0 = cc * 128 + w * 32;
  const int l31 = lane & 31, hi = lane >> 5;
  const size_t base = (size_t)bh * N * 128;
  const size_t vbase = (size_t)bh * 128 * N;
  const int Tblk = 2 * cc + 2;      // 64-wide tiles in the block sweep

  auto stage = [&](int tt, int buf) {
    const int kv0 = tt * 64;
#pragma unroll
    for (int j = 0; j < 4; ++j) {   // K: 64x128 shorts = 1024 chunks, 4/thread
      const int slot = j * 256 + t;
      const int krow = slot >> 4, kch = (slot & 15) ^ (krow & 7);
      async_ld16(&Ks[buf][slot * 8], Kb + base + (size_t)(kv0 + krow) * 128 + kch * 8);
    }
#pragma unroll
    for (int j = 0; j < 4; ++j) {   // V: 128x64 shorts = 1024 chunks, 4/thread
      const int slot = j * 256 + t;
      const int vrow = slot >> 3, vch = (slot & 7) ^ (vrow & 7);
      async_ld16(&Vs[buf][slot * 8], Vt + vbase + (size_t)vrow * N + kv0 + vch * 8);
    }
  };

  short8 qf[8];
#pragma unroll
  for (int s = 0; s < 8; ++s)
    qf[s] = *(const short8*)&Qb[base + (size_t)(q0 + l31) * 128 + s * 16 + hi * 8];

  f32x16 acc0 = {}, acc1 = {}, acc2 = {}, acc3 = {};
  float m_run = -1e30f, l_run = 0.f;

  stage(0, 0);
  stage(1, 1);

  for (int tt = 0; tt < Tblk; ++tt) {
    const int cur = tt & 1;
    if (tt < Tblk - 1) { asm volatile("s_waitcnt vmcnt(8)" ::: "memory"); }
    else               { asm volatile("s_waitcnt vmcnt(0)" ::: "memory"); }
    __builtin_amdgcn_sched_barrier(0);
    __builtin_amdgcn_s_barrier();

#pragma unroll
    for (int sb = 0; sb < 2; ++sb) {
      const int kv0 = tt * 64 + sb * 32;
      if (kv0 <= q0) {
        const bool masked = (kv0 == q0);

        short8 kf[8];
#pragma unroll
        for (int s = 0; s < 8; ++s)
          kf[s] = *(const short8*)&Ks[cur][(sb * 32 + l31) * 128 + ((2 * s + hi) ^ (l31 & 7)) * 8];
        short8 vf[8];
#pragma unroll
        for (int c2 = 0; c2 < 2; ++c2)
#pragma unroll
          for (int dblk = 0; dblk < 4; ++dblk) {
            const int row = dblk * 32 + l31;
            vf[c2 * 4 + dblk] =
                *(const short8*)&Vs[cur][row * 64 + ((sb * 4 + 2 * c2 + hi) ^ (row & 7)) * 8];
          }

        // two independent 4-deep MFMA chains -> half the serial accumulator latency
        f32x16 stA = {}, stB = {};
        __builtin_amdgcn_s_setprio(1);
#pragma unroll
        for (int s = 0; s < 4; ++s) {
          stA = __builtin_amdgcn_mfma_f32_32x32x16_bf16(kf[s], qf[s], stA, 0, 0, 0);
          stB = __builtin_amdgcn_mfma_f32_32x32x16_bf16(kf[s + 4], qf[s + 4], stB, 0, 0, 0);
        }
        __builtin_amdgcn_s_setprio(0);
        f32x16 st;
#pragma unroll
        for (int r = 0; r < 16; ++r) st[r] = stA[r] + stB[r];

        if (masked) {
          const int qg = q0 + l31;
#pragma unroll
          for (int r = 0; r < 16; ++r) {
            const int kvg = kv0 + (r & 3) + 8 * ((r >> 2) & 1) + 16 * (r >> 3) + 4 * hi;
            st[r] = (kvg > qg) ? -1e30f : st[r];
          }
        }
        // max tree as nested triples -> v_max3_f32
        const float g0 = fmaxf(fmaxf(st[0], st[1]), st[2]);
        const float g1 = fmaxf(fmaxf(st[3], st[4]), st[5]);
        const float g2 = fmaxf(fmaxf(st[6], st[7]), st[8]);
        const float g3 = fmaxf(fmaxf(st[9], st[10]), st[11]);
        const float g4 = fmaxf(fmaxf(st[12], st[13]), st[14]);
        const float h0 = fmaxf(fmaxf(g0, g1), g2);
        const float h1 = fmaxf(fmaxf(g3, g4), st[15]);
        float mt = fmaxf(h0, h1);
        mt = fmaxf(mt, __shfl_xor(mt, 32));

        float m_new = fmaxf(m_run, mt);
        const bool defer = __all(mt - m_run <= 8.f);  // T13
        if (defer) {
          m_new = m_run;
        } else {
          const float alpha = exp2_fast(m_run - m_new);
          l_run *= alpha;
#pragma unroll
          for (int r = 0; r < 16; ++r) {
            acc0[r] *= alpha; acc1[r] *= alpha; acc2[r] *= alpha; acc3[r] *= alpha;
          }
        }
        m_run = m_new;

#pragma unroll
        for (int r = 0; r < 16; ++r) st[r] = exp2_fast(st[r] - m_new);
        float s0 = (st[0] + st[1]) + (st[2] + st[3]), s1 = (st[4] + st[5]) + (st[6] + st[7]);
        float s2 = (st[8] + st[9]) + (st[10] + st[11]), s3 = (st[12] + st[13]) + (st[14] + st[15]);
        float lsum = (s0 + s1) + (s2 + s3);
        lsum += __shfl_xor(lsum, 32);
        l_run += lsum;

        short8 pB0, pB1;
#pragma unroll
        for (int c2 = 0; c2 < 2; ++c2) {
          const int o = c2 * 8;
          const uint32_t P01 = cvt_pk_bf16(st[o + 0], st[o + 1]);
          const uint32_t P23 = cvt_pk_bf16(st[o + 2], st[o + 3]);
          const uint32_t P45 = cvt_pk_bf16(st[o + 4], st[o + 5]);
          const uint32_t P67 = cvt_pk_bf16(st[o + 6], st[o + 7]);
          const uint32_t S01 = (uint32_t)__shfl_xor((int)P01, 32);
          const uint32_t S23 = (uint32_t)__shfl_xor((int)P23, 32);
          const uint32_t S45 = (uint32_t)__shfl_xor((int)P45, 32);
          const uint32_t S67 = (uint32_t)__shfl_xor((int)P67, 32);
          union { uint32_t ww[4]; short8 s8; } u;
          u.ww[0] = hi ? S45 : P01;
          u.ww[1] = hi ? S67 : P23;
          u.ww[2] = hi ? P45 : S01;
          u.ww[3] = hi ? P67 : S23;
          if (c2 == 0) pB0 = u.s8; else pB1 = u.s8;
        }

        __builtin_amdgcn_s_setprio(1);
        acc0 = __builtin_amdgcn_mfma_f32_32x32x16_bf16(vf[0], pB0, acc0, 0, 0, 0);
        acc1 = __builtin_amdgcn_mfma_f32_32x32x16_bf16(vf[1], pB0, acc1, 0, 0, 0);
        acc2 = __builtin_amdgcn_mfma_f32_32x32x16_bf16(vf[2], pB0, acc2, 0, 0, 0);
        acc3 = __builtin_amdgcn_mfma_f32_32x32x16_bf16(vf[3], pB0, acc3, 0, 0, 0);
        acc0 = __builtin_amdgcn_mfma_f32_32x32x16_bf16(vf[4], pB1, acc0, 0, 0, 0);
        acc1 = __builtin_amdgcn_mfma_f32_32x32x16_bf16(vf[5], pB1, acc1, 0, 0, 0);
        acc2 = __builtin_amdgcn_mfma_f32_32x32x16_bf16(vf[6], pB1, acc2, 0, 0, 0);
        acc3 = __builtin_amdgcn_mfma_f32_32x32x16_bf16(vf[7], pB1, acc3, 0, 0, 0);
        __builtin_amdgcn_s_setprio(0);
      }
    }

    asm volatile("s_waitcnt lgkmcnt(0)" ::: "memory");
    __builtin_amdgcn_sched_barrier(0);
    __builtin_amdgcn_s_barrier();
    if (tt + 2 < Tblk) stage(tt + 2, cur);
  }

  const float inv = 1.f / l_run;
  const size_t orow = (size_t)(b * N + q0 + l31) * 2048 + h * 128;
#pragma unroll
  for (int r = 0; r < 16; r += 2) {
    const int doff = (r & 3) + 8 * ((r >> 2) & 1) + 16 * (r >> 3) + 4 * hi;
    *(uint32_t*)&Ao[orow + 0  + doff] = cvt_pk_bf16(acc0[r] * inv, acc0[r + 1] * inv);
    *(uint32_t*)&Ao[orow + 32 + doff] = cvt_pk_bf16(acc1[r] * inv, acc1[r + 1] * inv);
    *(uint32_t*)&Ao[orow + 64 + doff] = cvt_pk_bf16(acc2[r] * inv, acc2[r + 1] * inv);
    *(uint32_t*)&Ao[orow + 96 + doff] = cvt_pk_bf16(acc3[r] * inv, acc3[r + 1] * inv);
  }
}

extern "C" void kernel_launch(void* const* d_in, const int* in_sizes, int n_in,
                              void* d_out, int out_size, void* d_ws, size_t ws_size,
                              hipStream_t stream) {
  const float* x      = (const float*)d_in[0];
  const int*   pos    = (const int*)d_in[1];
  const float* Wqkv   = (const float*)d_in[2];
  const float* Wproj  = (const float*)d_in[3];
  float* out = (float*)d_out;

  const int N = 2048, C = 2048;
  const int M = 2 * N;

  char* ws = (char*)d_ws;
  unsigned short* Xb      = (unsigned short*)(ws + 0);            // 16 MiB, reused as Ao
  unsigned short* Wqkv_t  = (unsigned short*)(ws + 16777216);     // 24 MiB
  unsigned short* Wproj_t = (unsigned short*)(ws + 41943040);     // 8 MiB
  float*          cosT    = (float*)(ws + 50331648);              // 512 KiB
  float*          sinT    = (float*)(ws + 50855936);              // 512 KiB
  unsigned short* Qb      = (unsigned short*)(ws + 100663296);    // 16 MiB
  unsigned short* Kb      = (unsigned short*)(ws + 117440512);    // 16 MiB
  unsigned short* Vt      = (unsigned short*)(ws + 134217728);    // 16 MiB
  unsigned short* Ao = Xb;

  cast_bf16_kernel<<<(M * C) / 1024, 256, 0, stream>>>(x, Xb, M * C);
  transpose_cast_kernel<<<dim3(3 * C / 32, C / 32), 256, 0, stream>>>(Wqkv, Wqkv_t, C, 3 * C);
  transpose_cast_kernel<<<dim3(C / 32, C / 32), 256, 0, stream>>>(Wproj, Wproj_t, C, C);
  rope_table<<<512, 256, 0, stream>>>(cosT, sinT);
  gemm_qkv_rope<<<dim3(3 * C / 128, M / 256), 512, 0, stream>>>(
      Xb, Wqkv_t, pos, cosT, sinT, Qb, Kb, Vt, M, 3 * C, C);
  flash_attn4<<<dim3(32, 16), 256, 0, stream>>>(Qb, Kb, Vt, Ao, N);
  gemm_bt64<0><<<dim3(C / 128, M / 256), 512, 0, stream>>>(Ao, Wproj_t, out, M, C, C);
}